// Round 1
// baseline (661.868 us; speedup 1.0000x reference)
//
#include <hip/hip_runtime.h>

// EdgeConv, factored: out[i] = deg(i)*(h[i]@Wd + b) + agg_src[i]@Ws + agg_ea[i]@We
// where W = [Wd; Ws; We] row blocks (64,64,16) of the (144,64) weight.
// CSR built on the fly each call (deterministic work), no float atomics.

static __device__ __forceinline__ float readlane_f(float v, int l) {
    return __uint_as_float((unsigned)__builtin_amdgcn_readlane((int)__float_as_uint(v), l));
}

__global__ void k_count(const int* __restrict__ dst, int* __restrict__ cnt, int E) {
    int e = blockIdx.x * 256 + threadIdx.x;
    if (e < E) atomicAdd(&cnt[dst[e]], 1);
}

__global__ void k_scan_reduce(const int* __restrict__ cnt, int* __restrict__ partial, int n) {
    __shared__ int sred[256];
    int t = threadIdx.x;
    int base = blockIdx.x * 1024 + t * 4;
    int s = 0;
#pragma unroll
    for (int k = 0; k < 4; k++) { int i = base + k; if (i < n) s += cnt[i]; }
    sred[t] = s;
    __syncthreads();
    for (int off = 128; off > 0; off >>= 1) {
        if (t < off) sred[t] += sred[t + off];
        __syncthreads();
    }
    if (t == 0) partial[blockIdx.x] = sred[0];
}

__global__ void k_scan_partials(int* __restrict__ partial, int nchunks) {
    __shared__ int sc[128];
    int t = threadIdx.x;
    int v = (t < nchunks) ? partial[t] : 0;
    sc[t] = v;
    __syncthreads();
    for (int off = 1; off < 128; off <<= 1) {
        int x = (t >= off) ? sc[t - off] : 0;
        __syncthreads();
        sc[t] += x;
        __syncthreads();
    }
    if (t < nchunks) partial[t] = sc[t] - v;  // exclusive prefix of chunk sums
}

__global__ void k_scan_final(const int* __restrict__ cnt, const int* __restrict__ partial,
                             int* __restrict__ row_ptr, int n, int Etot) {
    __shared__ int sc[256];
    int t = threadIdx.x;
    int base = blockIdx.x * 1024 + t * 4;
    int v[4]; int s = 0;
#pragma unroll
    for (int k = 0; k < 4; k++) { int i = base + k; v[k] = (i < n) ? cnt[i] : 0; s += v[k]; }
    sc[t] = s;
    __syncthreads();
    for (int off = 1; off < 256; off <<= 1) {
        int x = (t >= off) ? sc[t - off] : 0;
        __syncthreads();
        sc[t] += x;
        __syncthreads();
    }
    int run = partial[blockIdx.x] + (sc[t] - s);
#pragma unroll
    for (int k = 0; k < 4; k++) { int i = base + k; if (i < n) row_ptr[i] = run; run += v[k]; }
    if (blockIdx.x == 0 && t == 0) row_ptr[n] = Etot;
}

__global__ void k_copy(const int* __restrict__ a, int* __restrict__ b, int n) {
    int i = blockIdx.x * 256 + threadIdx.x;
    if (i < n) b[i] = a[i];
}

__global__ void k_fill(const int* __restrict__ src, const int* __restrict__ dst,
                       int* __restrict__ cursor, int* __restrict__ adj_src,
                       int* __restrict__ adj_eid, int E) {
    int e = blockIdx.x * 256 + threadIdx.x;
    if (e < E) {
        int d = dst[e];
        int p = atomicAdd(&cursor[d], 1);
        adj_src[p] = src[e];
        adj_eid[p] = e;
    }
}

// agg_ea[i][f] = sum of edge_attr[e][f] over incoming edges. Wave per node;
// lane = 16*g + f : 4-way edge parallelism (g), 16 features (f).
__global__ void k_agg_ea(const float* __restrict__ ea, const int* __restrict__ row_ptr,
                         const int* __restrict__ adj_eid, float* __restrict__ out, int N) {
    int wid = threadIdx.x >> 6, lane = threadIdx.x & 63;
    int node = blockIdx.x * 4 + wid;
    if (node >= N) return;
    int f = lane & 15, g = lane >> 4;
    int start = row_ptr[node], end = row_ptr[node + 1];
    float acc = 0.f;
    for (int e = start + g; e < end; e += 4)
        acc += ea[(size_t)adj_eid[e] * 16 + f];
    acc += __shfl_xor(acc, 16);
    acc += __shfl_xor(acc, 32);
    if (lane < 16) out[(size_t)node * 16 + f] = acc;
}

// Fused layer: wave per node, lane = output feature.
template <bool RELU>
__global__ __launch_bounds__(256) void k_layer(
    const float* __restrict__ h, const float* __restrict__ agg_ea,
    const int* __restrict__ row_ptr, const int* __restrict__ adj_src,
    const float* __restrict__ W, const float* __restrict__ bias,
    float* __restrict__ out, int N) {
    __shared__ float sW[144 * 64];
    for (int i = threadIdx.x; i < 144 * 64; i += 256) sW[i] = W[i];
    __syncthreads();

    int wid = threadIdx.x >> 6, lane = threadIdx.x & 63;
    float breg = bias[lane];

    for (int grp = blockIdx.x; grp * 4 < N; grp += gridDim.x) {
        int node = grp * 4 + wid;
        if (node >= N) continue;
        int start = row_ptr[node], end = row_ptr[node + 1];

        // gather-accumulate h[src] rows (4-way unrolled for MLP latency hiding)
        float acc = 0.f;
        int e = start;
        for (; e + 4 <= end; e += 4) {
            int s0 = adj_src[e], s1 = adj_src[e + 1], s2 = adj_src[e + 2], s3 = adj_src[e + 3];
            float v0 = h[(size_t)s0 * 64 + lane];
            float v1 = h[(size_t)s1 * 64 + lane];
            float v2 = h[(size_t)s2 * 64 + lane];
            float v3 = h[(size_t)s3 * 64 + lane];
            acc += v0; acc += v1; acc += v2; acc += v3;
        }
        for (; e < end; ++e) acc += h[(size_t)adj_src[e] * 64 + lane];

        float hval = h[(size_t)node * 64 + lane];
        float eaval = (lane < 16) ? agg_ea[(size_t)node * 16 + lane] : 0.f;
        float deg = (float)(end - start);

        float sum_h = 0.f, sum_a = 0.f, sum_e = 0.f;
#pragma unroll
        for (int f = 0; f < 64; f++) {
            sum_h = fmaf(readlane_f(hval, f), sW[f * 64 + lane], sum_h);
            sum_a = fmaf(readlane_f(acc, f), sW[(64 + f) * 64 + lane], sum_a);
        }
#pragma unroll
        for (int f = 0; f < 16; f++)
            sum_e = fmaf(readlane_f(eaval, f), sW[(128 + f) * 64 + lane], sum_e);

        float r = deg * (sum_h + breg) + sum_a + sum_e;
        if (RELU) r = fmaxf(r, 0.f);
        out[(size_t)node * 64 + lane] = r;
    }
}

extern "C" void kernel_launch(void* const* d_in, const int* in_sizes, int n_in,
                              void* d_out, int out_size, void* d_ws, size_t ws_size,
                              hipStream_t stream) {
    const float* x  = (const float*)d_in[0];
    const float* ea = (const float*)d_in[1];
    const int* eidx = (const int*)d_in[2];
    const float* W1 = (const float*)d_in[3];
    const float* b1 = (const float*)d_in[4];
    const float* W2 = (const float*)d_in[5];
    const float* b2 = (const float*)d_in[6];
    const float* W3 = (const float*)d_in[7];
    const float* b3 = (const float*)d_in[8];

    int N = in_sizes[0] / 64;
    int E = in_sizes[1] / 16;
    const int* src = eidx;       // edge_index[0]
    const int* dst = eidx + E;   // edge_index[1]

    char* p = (char*)d_ws;
    auto alloc = [&](size_t bytes) {
        char* r = p;
        p += (bytes + 255) & ~(size_t)255;
        return r;
    };
    int*   row_ptr = (int*)alloc((size_t)(N + 1) * 4);
    int*   cnt     = (int*)alloc((size_t)N * 4);       // reused as cursor
    int*   partial = (int*)alloc(1024 * 4);
    int*   adj_src = (int*)alloc((size_t)E * 4);
    int*   adj_eid = (int*)alloc((size_t)E * 4);
    float* agg_ea  = (float*)alloc((size_t)N * 16 * 4);
    float* h1      = (float*)alloc((size_t)N * 64 * 4);
    float* h2      = (float*)alloc((size_t)N * 64 * 4);

    hipMemsetAsync(cnt, 0, (size_t)N * 4, stream);

    int gE = (E + 255) / 256;
    k_count<<<gE, 256, 0, stream>>>(dst, cnt, E);

    int nchunks = (N + 1023) / 1024;  // 98 for N=100000 (<=128 required)
    k_scan_reduce<<<nchunks, 256, 0, stream>>>(cnt, partial, N);
    k_scan_partials<<<1, 128, 0, stream>>>(partial, nchunks);
    k_scan_final<<<nchunks, 256, 0, stream>>>(cnt, partial, row_ptr, N, E);
    k_copy<<<(N + 255) / 256, 256, 0, stream>>>(row_ptr, cnt, N);  // cursor = row_ptr
    k_fill<<<gE, 256, 0, stream>>>(src, dst, cnt, adj_src, adj_eid, E);

    int gN = (N + 3) / 4;
    k_agg_ea<<<gN, 256, 0, stream>>>(ea, row_ptr, adj_eid, agg_ea, N);

    int gL = 2048;  // grid-stride: amortize 36KB W->LDS load ~50x per block
    k_layer<true ><<<gL, 256, 0, stream>>>(x,  agg_ea, row_ptr, adj_src, W1, b1, h1, N);
    k_layer<true ><<<gL, 256, 0, stream>>>(h1, agg_ea, row_ptr, adj_src, W2, b2, h2, N);
    k_layer<false><<<gL, 256, 0, stream>>>(h2, agg_ea, row_ptr, adj_src, W3, b3, (float*)d_out, N);
}

// Round 2
// 573.833 us; speedup vs baseline: 1.1534x; 1.1534x over previous
//
#include <hip/hip_runtime.h>

// EdgeConv, factored twice:
//   out = deg ⊙ (H@Wd + b + (agg_ea/deg)@We) + A·(H@Ws)
//       = deg ⊙ S' + gather_sum(Q),  [S'|Q] = [H|ea'] @ W80  (dense GEMM)
// so the per-edge work is a pure 256B gather+add and the matmul is a dense
// register-tiled fp32 GEMM. CSR built per call; no float atomics.

__global__ void k_count(const int* __restrict__ dst, int* __restrict__ cnt, int E) {
    int e = blockIdx.x * 256 + threadIdx.x;
    if (e < E) atomicAdd(&cnt[dst[e]], 1);
}

__global__ void k_scan_reduce(const int* __restrict__ cnt, int* __restrict__ partial, int n) {
    __shared__ int sred[256];
    int t = threadIdx.x;
    int base = blockIdx.x * 1024 + t * 4;
    int s = 0;
#pragma unroll
    for (int k = 0; k < 4; k++) { int i = base + k; if (i < n) s += cnt[i]; }
    sred[t] = s;
    __syncthreads();
    for (int off = 128; off > 0; off >>= 1) {
        if (t < off) sred[t] += sred[t + off];
        __syncthreads();
    }
    if (t == 0) partial[blockIdx.x] = sred[0];
}

__global__ void k_scan_partials(int* __restrict__ partial, int nchunks) {
    __shared__ int sc[128];
    int t = threadIdx.x;
    int v = (t < nchunks) ? partial[t] : 0;
    sc[t] = v;
    __syncthreads();
    for (int off = 1; off < 128; off <<= 1) {
        int x = (t >= off) ? sc[t - off] : 0;
        __syncthreads();
        sc[t] += x;
        __syncthreads();
    }
    if (t < nchunks) partial[t] = sc[t] - v;  // exclusive prefix of chunk sums
}

__global__ void k_scan_final(const int* __restrict__ cnt, const int* __restrict__ partial,
                             int* __restrict__ row_ptr, int* __restrict__ cursor,
                             int n, int Etot) {
    __shared__ int sc[256];
    int t = threadIdx.x;
    int base = blockIdx.x * 1024 + t * 4;
    int v[4]; int s = 0;
#pragma unroll
    for (int k = 0; k < 4; k++) { int i = base + k; v[k] = (i < n) ? cnt[i] : 0; s += v[k]; }
    sc[t] = s;
    __syncthreads();
    for (int off = 1; off < 256; off <<= 1) {
        int x = (t >= off) ? sc[t - off] : 0;
        __syncthreads();
        sc[t] += x;
        __syncthreads();
    }
    int run = partial[blockIdx.x] + (sc[t] - s);
#pragma unroll
    for (int k = 0; k < 4; k++) {
        int i = base + k;
        if (i < n) { row_ptr[i] = run; cursor[i] = run; }
        run += v[k];
    }
    if (blockIdx.x == 0 && t == 0) row_ptr[n] = Etot;
}

__global__ void k_fill(const int* __restrict__ src, const int* __restrict__ dst,
                       int* __restrict__ cursor, int* __restrict__ adj_src,
                       int* __restrict__ adj_eid, int E) {
    int e = blockIdx.x * 256 + threadIdx.x;
    if (e < E) {
        int d = dst[e];
        int p = atomicAdd(&cursor[d], 1);
        adj_src[p] = src[e];
        adj_eid[p] = e;
    }
}

// ea'[i] = (sum of edge_attr over incoming edges) / deg(i)
__global__ void k_agg_ea(const float* __restrict__ ea, const int* __restrict__ row_ptr,
                         const int* __restrict__ adj_eid, float* __restrict__ out, int N) {
    int wid = threadIdx.x >> 6, lane = threadIdx.x & 63;
    int node = blockIdx.x * 4 + wid;
    if (node >= N) return;
    int f = lane & 15, g = lane >> 4;
    int start = row_ptr[node], end = row_ptr[node + 1];
    float acc = 0.f;
    for (int e = start + g; e < end; e += 4)
        acc += ea[(size_t)adj_eid[e] * 16 + f];
    acc += __shfl_xor(acc, 16);
    acc += __shfl_xor(acc, 32);
    if (lane < 16) {
        float d = (float)(end - start);
        out[(size_t)node * 16 + f] = (d > 0.f) ? acc / d : 0.f;
    }
}

// Dense GEMM: [S'|Q](N x 128) = [H|ea'](N x 80) @ W80, bias folded into S'.
// W80 row remap from original W(144 x 64) done at LDS-load time.
// Tile: 32 rows x 128 cols, 256 threads, 4x4 register micro-tile.
__global__ __launch_bounds__(256) void k_gemm(
    const float* __restrict__ h, const float* __restrict__ eap,
    const float* __restrict__ W, const float* __restrict__ bias,
    float* __restrict__ Sp, float* __restrict__ Q, int N) {
    __shared__ float sInT[80 * 36];   // input tile, transposed, pad 36 (16B-aligned rows)
    __shared__ float sW[80 * 128];

    int tid = threadIdx.x;
    int r0 = blockIdx.x * 32;

    // H tile (32x64) -> sInT[k][i], k<64
#pragma unroll
    for (int rep = 0; rep < 2; ++rep) {
        int vid = rep * 256 + tid;            // 512 float4
        int i = vid >> 4;
        int j4 = (vid & 15) * 4;
        int row = r0 + i;
        float4 v = (row < N) ? *reinterpret_cast<const float4*>(&h[(size_t)row * 64 + j4])
                             : float4{0.f, 0.f, 0.f, 0.f};
        sInT[(j4 + 0) * 36 + i] = v.x;
        sInT[(j4 + 1) * 36 + i] = v.y;
        sInT[(j4 + 2) * 36 + i] = v.z;
        sInT[(j4 + 3) * 36 + i] = v.w;
    }
    // ea' tile (32x16) -> sInT[64+f][i]
    if (tid < 128) {
        int i = tid >> 2;
        int f4 = (tid & 3) * 4;
        int row = r0 + i;
        float4 v = (row < N) ? *reinterpret_cast<const float4*>(&eap[(size_t)row * 16 + f4])
                             : float4{0.f, 0.f, 0.f, 0.f};
        sInT[(64 + f4 + 0) * 36 + i] = v.x;
        sInT[(64 + f4 + 1) * 36 + i] = v.y;
        sInT[(64 + f4 + 2) * 36 + i] = v.z;
        sInT[(64 + f4 + 3) * 36 + i] = v.w;
    }
    // W80 (80x128) with row remap: cols<64 from [Wd;We], cols>=64 from [Ws;0]
#pragma unroll
    for (int rep = 0; rep < 10; ++rep) {
        int vid = rep * 256 + tid;            // 2560 float4
        int k = vid >> 5;
        int c4 = (vid & 31) * 4;
        float4 v;
        if (c4 < 64) {
            const float* s = (k < 64) ? &W[k * 64 + c4] : &W[(128 + k - 64) * 64 + c4];
            v = *reinterpret_cast<const float4*>(s);
        } else {
            if (k < 64) v = *reinterpret_cast<const float4*>(&W[(64 + k) * 64 + (c4 - 64)]);
            else        v = float4{0.f, 0.f, 0.f, 0.f};
        }
        *reinterpret_cast<float4*>(&sW[k * 128 + c4]) = v;
    }
    __syncthreads();

    int rg = tid >> 5, cg = tid & 31;
    int c0 = cg * 4;
    float acc[4][4] = {};
#pragma unroll 8
    for (int k = 0; k < 80; ++k) {
        float4 a = *reinterpret_cast<const float4*>(&sInT[k * 36 + rg * 4]);
        float4 w = *reinterpret_cast<const float4*>(&sW[k * 128 + c0]);
        float av[4] = {a.x, a.y, a.z, a.w};
        float wv[4] = {w.x, w.y, w.z, w.w};
#pragma unroll
        for (int i = 0; i < 4; ++i)
#pragma unroll
            for (int j = 0; j < 4; ++j)
                acc[i][j] = fmaf(av[i], wv[j], acc[i][j]);
    }

    float4 bv = {0.f, 0.f, 0.f, 0.f};
    if (c0 < 64) bv = *reinterpret_cast<const float4*>(&bias[c0]);
#pragma unroll
    for (int i = 0; i < 4; ++i) {
        int row = r0 + rg * 4 + i;
        if (row >= N) continue;
        if (c0 < 64) {
            float4 o = {acc[i][0] + bv.x, acc[i][1] + bv.y, acc[i][2] + bv.z, acc[i][3] + bv.w};
            *reinterpret_cast<float4*>(&Sp[(size_t)row * 64 + c0]) = o;
        } else {
            float4 o = {acc[i][0], acc[i][1], acc[i][2], acc[i][3]};
            *reinterpret_cast<float4*>(&Q[(size_t)row * 64 + (c0 - 64)]) = o;
        }
    }
}

// out[i] = deg(i) * S'[i] + sum_{e: dst=i} Q[src[e]]   (+ ReLU)
template <bool RELU>
__global__ __launch_bounds__(256) void k_aggregate(
    const float* __restrict__ Sp, const float* __restrict__ Q,
    const int* __restrict__ row_ptr, const int* __restrict__ adj_src,
    float* __restrict__ out, int N) {
    int wid = threadIdx.x >> 6, lane = threadIdx.x & 63;
    int node = blockIdx.x * 4 + wid;
    if (node >= N) return;
    int start = row_ptr[node], end = row_ptr[node + 1];
    float acc = 0.f;
    int e = start;
    for (; e + 4 <= end; e += 4) {
        int s0 = adj_src[e], s1 = adj_src[e + 1], s2 = adj_src[e + 2], s3 = adj_src[e + 3];
        float v0 = Q[(size_t)s0 * 64 + lane];
        float v1 = Q[(size_t)s1 * 64 + lane];
        float v2 = Q[(size_t)s2 * 64 + lane];
        float v3 = Q[(size_t)s3 * 64 + lane];
        acc += v0; acc += v1; acc += v2; acc += v3;
    }
    for (; e < end; ++e) acc += Q[(size_t)adj_src[e] * 64 + lane];
    float r = (float)(end - start) * Sp[(size_t)node * 64 + lane] + acc;
    if (RELU) r = fmaxf(r, 0.f);
    out[(size_t)node * 64 + lane] = r;
}

extern "C" void kernel_launch(void* const* d_in, const int* in_sizes, int n_in,
                              void* d_out, int out_size, void* d_ws, size_t ws_size,
                              hipStream_t stream) {
    const float* x  = (const float*)d_in[0];
    const float* ea = (const float*)d_in[1];
    const int* eidx = (const int*)d_in[2];
    const float* W1 = (const float*)d_in[3];
    const float* b1 = (const float*)d_in[4];
    const float* W2 = (const float*)d_in[5];
    const float* b2 = (const float*)d_in[6];
    const float* W3 = (const float*)d_in[7];
    const float* b3 = (const float*)d_in[8];

    int N = in_sizes[0] / 64;
    int E = in_sizes[1] / 16;
    const int* src = eidx;       // edge_index[0]
    const int* dst = eidx + E;   // edge_index[1]

    char* p = (char*)d_ws;
    auto alloc = [&](size_t bytes) {
        char* r = p;
        p += (bytes + 255) & ~(size_t)255;
        return r;
    };
    int*   row_ptr = (int*)alloc((size_t)(N + 1) * 4);
    int*   cursor  = (int*)alloc((size_t)N * 4);       // also cnt during build
    int*   partial = (int*)alloc(1024 * 4);
    int*   adj_src = (int*)alloc((size_t)E * 4);
    int*   adj_eid = (int*)alloc((size_t)E * 4);
    float* eap     = (float*)alloc((size_t)N * 16 * 4);
    float* hbuf    = (float*)alloc((size_t)N * 64 * 4);   // shared h buffer (layer1 out, layer2 in+out)
    float* Sbuf    = (float*)alloc((size_t)N * 64 * 4);
    float* Qbuf    = (float*)alloc((size_t)N * 64 * 4);

    hipMemsetAsync(cursor, 0, (size_t)N * 4, stream);

    int gE = (E + 255) / 256;
    k_count<<<gE, 256, 0, stream>>>(dst, cursor, E);

    int nchunks = (N + 1023) / 1024;  // 98 for N=100000 (<=128 required)
    k_scan_reduce<<<nchunks, 256, 0, stream>>>(cursor, partial, N);
    k_scan_partials<<<1, 128, 0, stream>>>(partial, nchunks);
    k_scan_final<<<nchunks, 256, 0, stream>>>(cursor, partial, row_ptr, cursor, N, E);
    k_fill<<<gE, 256, 0, stream>>>(src, dst, cursor, adj_src, adj_eid, E);

    int gN4 = (N + 3) / 4;
    k_agg_ea<<<gN4, 256, 0, stream>>>(ea, row_ptr, adj_eid, eap, N);

    int gT = (N + 31) / 32;  // GEMM row tiles

    // layer 1: x -> hbuf
    k_gemm<<<gT, 256, 0, stream>>>(x, eap, W1, b1, Sbuf, Qbuf, N);
    k_aggregate<true ><<<gN4, 256, 0, stream>>>(Sbuf, Qbuf, row_ptr, adj_src, hbuf, N);
    // layer 2: hbuf -> hbuf (gemm consumes hbuf fully before aggregate rewrites it)
    k_gemm<<<gT, 256, 0, stream>>>(hbuf, eap, W2, b2, Sbuf, Qbuf, N);
    k_aggregate<true ><<<gN4, 256, 0, stream>>>(Sbuf, Qbuf, row_ptr, adj_src, hbuf, N);
    // layer 3: hbuf -> d_out
    k_gemm<<<gT, 256, 0, stream>>>(hbuf, eap, W3, b3, Sbuf, Qbuf, N);
    k_aggregate<false><<<gN4, 256, 0, stream>>>(Sbuf, Qbuf, row_ptr, adj_src, (float*)d_out, N);
}

// Round 3
// 531.275 us; speedup vs baseline: 1.2458x; 1.0801x over previous
//
#include <hip/hip_runtime.h>

// EdgeConv, factored twice:
//   out = deg ⊙ (H@Wd + b + (agg_ea/deg)@We) + A·(H@Ws)
//       = deg ⊙ S' + gather_sum(Q),  [S'|Q] = [H|ea'] @ W80  (dense GEMM)
// CSR built per call; no float atomics. adj packed as int2(src,eid): one 8B
// scatter per edge (halves the XCD-amplified scatter line-visits vs 2x4B).

__global__ void k_count(const int* __restrict__ dst, int* __restrict__ cnt, int E) {
    int e = blockIdx.x * 256 + threadIdx.x;
    if (e < E) atomicAdd(&cnt[dst[e]], 1);
}

__global__ void k_scan_reduce(const int* __restrict__ cnt, int* __restrict__ partial, int n) {
    __shared__ int sred[256];
    int t = threadIdx.x;
    int base = blockIdx.x * 1024 + t * 4;
    int s = 0;
#pragma unroll
    for (int k = 0; k < 4; k++) { int i = base + k; if (i < n) s += cnt[i]; }
    sred[t] = s;
    __syncthreads();
    for (int off = 128; off > 0; off >>= 1) {
        if (t < off) sred[t] += sred[t + off];
        __syncthreads();
    }
    if (t == 0) partial[blockIdx.x] = sred[0];
}

__global__ void k_scan_partials(int* __restrict__ partial, int nchunks) {
    __shared__ int sc[128];
    int t = threadIdx.x;
    int v = (t < nchunks) ? partial[t] : 0;
    sc[t] = v;
    __syncthreads();
    for (int off = 1; off < 128; off <<= 1) {
        int x = (t >= off) ? sc[t - off] : 0;
        __syncthreads();
        sc[t] += x;
        __syncthreads();
    }
    if (t < nchunks) partial[t] = sc[t] - v;  // exclusive prefix of chunk sums
}

__global__ void k_scan_final(const int* __restrict__ cnt, const int* __restrict__ partial,
                             int* __restrict__ row_ptr, int* __restrict__ cursor,
                             int n, int Etot) {
    __shared__ int sc[256];
    int t = threadIdx.x;
    int base = blockIdx.x * 1024 + t * 4;
    int v[4]; int s = 0;
#pragma unroll
    for (int k = 0; k < 4; k++) { int i = base + k; v[k] = (i < n) ? cnt[i] : 0; s += v[k]; }
    sc[t] = s;
    __syncthreads();
    for (int off = 1; off < 256; off <<= 1) {
        int x = (t >= off) ? sc[t - off] : 0;
        __syncthreads();
        sc[t] += x;
        __syncthreads();
    }
    int run = partial[blockIdx.x] + (sc[t] - s);
#pragma unroll
    for (int k = 0; k < 4; k++) {
        int i = base + k;
        if (i < n) { row_ptr[i] = run; cursor[i] = run; }
        run += v[k];
    }
    if (blockIdx.x == 0 && t == 0) row_ptr[n] = Etot;
}

__global__ void k_fill(const int* __restrict__ src, const int* __restrict__ dst,
                       int* __restrict__ cursor, int2* __restrict__ adj, int E) {
    int e = blockIdx.x * 256 + threadIdx.x;
    if (e < E) {
        int d = dst[e];
        int p = atomicAdd(&cursor[d], 1);
        adj[p] = make_int2(src[e], e);   // one 8B scatter instead of two 4B
    }
}

// ea'[i] = (sum of edge_attr over incoming edges) / deg(i)
// Wave per node: 4 lanes/row (float4), 16 edge-groups in parallel.
__global__ void k_agg_ea(const float* __restrict__ ea, const int* __restrict__ row_ptr,
                         const int2* __restrict__ adj, float* __restrict__ out, int N) {
    int wid = threadIdx.x >> 6, lane = threadIdx.x & 63;
    int node = blockIdx.x * 4 + wid;
    if (node >= N) return;
    int q = lane & 3, g = lane >> 2;
    int start = row_ptr[node], end = row_ptr[node + 1];
    float4 acc = {0.f, 0.f, 0.f, 0.f};
    for (int e = start + g; e < end; e += 16) {
        int eid = adj[e].y;
        float4 v = *reinterpret_cast<const float4*>(&ea[(size_t)eid * 16 + q * 4]);
        acc.x += v.x; acc.y += v.y; acc.z += v.z; acc.w += v.w;
    }
#pragma unroll
    for (int m = 4; m <= 32; m <<= 1) {
        acc.x += __shfl_xor(acc.x, m);
        acc.y += __shfl_xor(acc.y, m);
        acc.z += __shfl_xor(acc.z, m);
        acc.w += __shfl_xor(acc.w, m);
    }
    if (lane < 4) {
        float d = (end > start) ? 1.f / (float)(end - start) : 0.f;
        float4 o = {acc.x * d, acc.y * d, acc.z * d, acc.w * d};
        *reinterpret_cast<float4*>(&out[(size_t)node * 16 + q * 4]) = o;
    }
}

// Dense GEMM: [S'|Q](N x 128) = [H|ea'](N x 80) @ W80, bias folded into S'.
__global__ __launch_bounds__(256) void k_gemm(
    const float* __restrict__ h, const float* __restrict__ eap,
    const float* __restrict__ W, const float* __restrict__ bias,
    float* __restrict__ Sp, float* __restrict__ Q, int N) {
    __shared__ float sInT[80 * 36];   // input tile, transposed, pad 36
    __shared__ float sW[80 * 128];

    int tid = threadIdx.x;
    int r0 = blockIdx.x * 32;

#pragma unroll
    for (int rep = 0; rep < 2; ++rep) {
        int vid = rep * 256 + tid;            // 512 float4
        int i = vid >> 4;
        int j4 = (vid & 15) * 4;
        int row = r0 + i;
        float4 v = (row < N) ? *reinterpret_cast<const float4*>(&h[(size_t)row * 64 + j4])
                             : float4{0.f, 0.f, 0.f, 0.f};
        sInT[(j4 + 0) * 36 + i] = v.x;
        sInT[(j4 + 1) * 36 + i] = v.y;
        sInT[(j4 + 2) * 36 + i] = v.z;
        sInT[(j4 + 3) * 36 + i] = v.w;
    }
    if (tid < 128) {
        int i = tid >> 2;
        int f4 = (tid & 3) * 4;
        int row = r0 + i;
        float4 v = (row < N) ? *reinterpret_cast<const float4*>(&eap[(size_t)row * 16 + f4])
                             : float4{0.f, 0.f, 0.f, 0.f};
        sInT[(64 + f4 + 0) * 36 + i] = v.x;
        sInT[(64 + f4 + 1) * 36 + i] = v.y;
        sInT[(64 + f4 + 2) * 36 + i] = v.z;
        sInT[(64 + f4 + 3) * 36 + i] = v.w;
    }
    // W80 (80x128) with row remap: cols<64 from [Wd;We], cols>=64 from [Ws;0]
#pragma unroll
    for (int rep = 0; rep < 10; ++rep) {
        int vid = rep * 256 + tid;            // 2560 float4
        int k = vid >> 5;
        int c4 = (vid & 31) * 4;
        float4 v;
        if (c4 < 64) {
            const float* s = (k < 64) ? &W[k * 64 + c4] : &W[(128 + k - 64) * 64 + c4];
            v = *reinterpret_cast<const float4*>(s);
        } else {
            if (k < 64) v = *reinterpret_cast<const float4*>(&W[(64 + k) * 64 + (c4 - 64)]);
            else        v = float4{0.f, 0.f, 0.f, 0.f};
        }
        *reinterpret_cast<float4*>(&sW[k * 128 + c4]) = v;
    }
    __syncthreads();

    int rg = tid >> 5, cg = tid & 31;
    int c0 = cg * 4;
    float acc[4][4] = {};
#pragma unroll 8
    for (int k = 0; k < 80; ++k) {
        float4 a = *reinterpret_cast<const float4*>(&sInT[k * 36 + rg * 4]);
        float4 w = *reinterpret_cast<const float4*>(&sW[k * 128 + c0]);
        float av[4] = {a.x, a.y, a.z, a.w};
        float wv[4] = {w.x, w.y, w.z, w.w};
#pragma unroll
        for (int i = 0; i < 4; ++i)
#pragma unroll
            for (int j = 0; j < 4; ++j)
                acc[i][j] = fmaf(av[i], wv[j], acc[i][j]);
    }

    float4 bv = {0.f, 0.f, 0.f, 0.f};
    if (c0 < 64) bv = *reinterpret_cast<const float4*>(&bias[c0]);
#pragma unroll
    for (int i = 0; i < 4; ++i) {
        int row = r0 + rg * 4 + i;
        if (row >= N) continue;
        if (c0 < 64) {
            float4 o = {acc[i][0] + bv.x, acc[i][1] + bv.y, acc[i][2] + bv.z, acc[i][3] + bv.w};
            *reinterpret_cast<float4*>(&Sp[(size_t)row * 64 + c0]) = o;
        } else {
            float4 o = {acc[i][0], acc[i][1], acc[i][2], acc[i][3]};
            *reinterpret_cast<float4*>(&Q[(size_t)row * 64 + (c0 - 64)]) = o;
        }
    }
}

// out[i] = deg(i) * S'[i] + sum_{e: dst=i} Q[src[e]]   (+ ReLU)
// Wave per node: 16 lanes/row (float4), 4 edge-groups, 4-deep unroll.
template <bool RELU>
__global__ __launch_bounds__(256) void k_aggregate(
    const float* __restrict__ Sp, const float* __restrict__ Q,
    const int* __restrict__ row_ptr, const int2* __restrict__ adj,
    float* __restrict__ out, int N) {
    int wid = threadIdx.x >> 6, lane = threadIdx.x & 63;
    int node = blockIdx.x * 4 + wid;
    if (node >= N) return;
    int f4 = lane & 15, g = lane >> 4;
    int start = row_ptr[node], end = row_ptr[node + 1];
    float4 acc = {0.f, 0.f, 0.f, 0.f};
    int e = start + g;
    for (; e + 12 < end; e += 16) {
        int s0 = adj[e].x, s1 = adj[e + 4].x, s2 = adj[e + 8].x, s3 = adj[e + 12].x;
        float4 v0 = *reinterpret_cast<const float4*>(&Q[(size_t)s0 * 64 + f4 * 4]);
        float4 v1 = *reinterpret_cast<const float4*>(&Q[(size_t)s1 * 64 + f4 * 4]);
        float4 v2 = *reinterpret_cast<const float4*>(&Q[(size_t)s2 * 64 + f4 * 4]);
        float4 v3 = *reinterpret_cast<const float4*>(&Q[(size_t)s3 * 64 + f4 * 4]);
        acc.x += v0.x + v1.x + v2.x + v3.x;
        acc.y += v0.y + v1.y + v2.y + v3.y;
        acc.z += v0.z + v1.z + v2.z + v3.z;
        acc.w += v0.w + v1.w + v2.w + v3.w;
    }
    for (; e < end; e += 4) {
        int s = adj[e].x;
        float4 v = *reinterpret_cast<const float4*>(&Q[(size_t)s * 64 + f4 * 4]);
        acc.x += v.x; acc.y += v.y; acc.z += v.z; acc.w += v.w;
    }
    acc.x += __shfl_xor(acc.x, 16); acc.y += __shfl_xor(acc.y, 16);
    acc.z += __shfl_xor(acc.z, 16); acc.w += __shfl_xor(acc.w, 16);
    acc.x += __shfl_xor(acc.x, 32); acc.y += __shfl_xor(acc.y, 32);
    acc.z += __shfl_xor(acc.z, 32); acc.w += __shfl_xor(acc.w, 32);
    if (lane < 16) {
        float deg = (float)(end - start);
        float4 s = *reinterpret_cast<const float4*>(&Sp[(size_t)node * 64 + f4 * 4]);
        float4 r = {deg * s.x + acc.x, deg * s.y + acc.y,
                    deg * s.z + acc.z, deg * s.w + acc.w};
        if (RELU) {
            r.x = fmaxf(r.x, 0.f); r.y = fmaxf(r.y, 0.f);
            r.z = fmaxf(r.z, 0.f); r.w = fmaxf(r.w, 0.f);
        }
        *reinterpret_cast<float4*>(&out[(size_t)node * 64 + f4 * 4]) = r;
    }
}

extern "C" void kernel_launch(void* const* d_in, const int* in_sizes, int n_in,
                              void* d_out, int out_size, void* d_ws, size_t ws_size,
                              hipStream_t stream) {
    const float* x  = (const float*)d_in[0];
    const float* ea = (const float*)d_in[1];
    const int* eidx = (const int*)d_in[2];
    const float* W1 = (const float*)d_in[3];
    const float* b1 = (const float*)d_in[4];
    const float* W2 = (const float*)d_in[5];
    const float* b2 = (const float*)d_in[6];
    const float* W3 = (const float*)d_in[7];
    const float* b3 = (const float*)d_in[8];

    int N = in_sizes[0] / 64;
    int E = in_sizes[1] / 16;
    const int* src = eidx;       // edge_index[0]
    const int* dst = eidx + E;   // edge_index[1]

    char* p = (char*)d_ws;
    auto alloc = [&](size_t bytes) {
        char* r = p;
        p += (bytes + 255) & ~(size_t)255;
        return r;
    };
    int*   row_ptr = (int*)alloc((size_t)(N + 1) * 4);
    int*   cursor  = (int*)alloc((size_t)N * 4);       // also cnt during build
    int*   partial = (int*)alloc(1024 * 4);
    int2*  adj     = (int2*)alloc((size_t)E * 8);
    float* eap     = (float*)alloc((size_t)N * 16 * 4);
    float* hbuf    = (float*)alloc((size_t)N * 64 * 4);
    float* Sbuf    = (float*)alloc((size_t)N * 64 * 4);
    float* Qbuf    = (float*)alloc((size_t)N * 64 * 4);

    hipMemsetAsync(cursor, 0, (size_t)N * 4, stream);

    int gE = (E + 255) / 256;
    k_count<<<gE, 256, 0, stream>>>(dst, cursor, E);

    int nchunks = (N + 1023) / 1024;  // 98 for N=100000 (<=128 required)
    k_scan_reduce<<<nchunks, 256, 0, stream>>>(cursor, partial, N);
    k_scan_partials<<<1, 128, 0, stream>>>(partial, nchunks);
    k_scan_final<<<nchunks, 256, 0, stream>>>(cursor, partial, row_ptr, cursor, N, E);
    k_fill<<<gE, 256, 0, stream>>>(src, dst, cursor, adj, E);

    int gN4 = (N + 3) / 4;
    k_agg_ea<<<gN4, 256, 0, stream>>>(ea, row_ptr, adj, eap, N);

    int gT = (N + 31) / 32;  // GEMM row tiles

    // layer 1: x -> hbuf
    k_gemm<<<gT, 256, 0, stream>>>(x, eap, W1, b1, Sbuf, Qbuf, N);
    k_aggregate<true ><<<gN4, 256, 0, stream>>>(Sbuf, Qbuf, row_ptr, adj, hbuf, N);
    // layer 2: hbuf -> hbuf (gemm consumes hbuf fully before aggregate rewrites it)
    k_gemm<<<gT, 256, 0, stream>>>(hbuf, eap, W2, b2, Sbuf, Qbuf, N);
    k_aggregate<true ><<<gN4, 256, 0, stream>>>(Sbuf, Qbuf, row_ptr, adj, hbuf, N);
    // layer 3: hbuf -> d_out
    k_gemm<<<gT, 256, 0, stream>>>(hbuf, eap, W3, b3, Sbuf, Qbuf, N);
    k_aggregate<false><<<gN4, 256, 0, stream>>>(Sbuf, Qbuf, row_ptr, adj, (float*)d_out, N);
}

// Round 4
// 387.918 us; speedup vs baseline: 1.7062x; 1.3696x over previous
//
#include <hip/hip_runtime.h>
#include <stdint.h>

// EdgeConv, factored twice:
//   out = deg ⊙ (H@Wd + b + (agg_ea/deg)@We) + A·(H@Ws)
//       = deg ⊙ S' + gather_sum(Q),  [S'|Q] = [H|ea'] @ W80  (dense GEMM)
// CSR build = bucketed counting sort: all random scatter contained in LDS,
// all global writes coalesced. No float atomics anywhere.

#define BKT_SHIFT 9
#define BKT_NODES 512          // nodes per bucket
#define PART_EDGES 4096        // edges per k_part block
#define CSR_CAP 12288          // LDS staging entries in k_csr (96KB)

typedef unsigned long long u64;

// ---- bucket histogram: bcnt[b] = #edges with dst in bucket b ----
__global__ __launch_bounds__(256) void k_hist(const int* __restrict__ dst,
                                              int* __restrict__ bcnt, int E) {
    __shared__ int h[256];
    int t = threadIdx.x;
    h[t] = 0;
    __syncthreads();
    int i0 = blockIdx.x * PART_EDGES + t;
#pragma unroll
    for (int k = 0; k < 16; ++k) {
        int i = i0 + k * 256;
        if (i < E) atomicAdd(&h[dst[i] >> BKT_SHIFT], 1);
    }
    __syncthreads();
    int v = h[t];
    if (v) atomicAdd(&bcnt[t], v);
}

// ---- scan bucket counts -> bbase (exclusive), init cursors ----
__global__ __launch_bounds__(256) void k_bucket_scan(const int* __restrict__ bcnt,
                                                     int* __restrict__ bbase,
                                                     int* __restrict__ bcur,
                                                     int* __restrict__ row_ptr,
                                                     int NB, int N, int E) {
    __shared__ int sc[256];
    int t = threadIdx.x;
    int v = (t < NB) ? bcnt[t] : 0;
    sc[t] = v;
    __syncthreads();
    for (int off = 1; off < 256; off <<= 1) {
        int x = (t >= off) ? sc[t - off] : 0;
        __syncthreads();
        sc[t] += x;
        __syncthreads();
    }
    int ex = sc[t] - v;
    if (t < NB) { bbase[t] = ex; bcur[t] = ex; }
    if (t == 0) { bbase[NB] = E; row_ptr[N] = E; }
}

// ---- partition: pack (dst:17|src:17|eid:21) u64, local counting sort by
//      bucket in LDS, coalesced run writes to ebuf ----
__global__ __launch_bounds__(256) void k_part(const int* __restrict__ src,
                                              const int* __restrict__ dst,
                                              int* __restrict__ bcur,
                                              u64* __restrict__ ebuf, int E) {
    __shared__ u64 k1[PART_EDGES];
    __shared__ u64 k2[PART_EDGES];
    __shared__ int hist[256], sscan[256], lbase[256], runb[256], cur[256];
    int t = threadIdx.x;
    int e0 = blockIdx.x * PART_EDGES;
    int n = min(PART_EDGES, E - e0);

    hist[t] = 0;
    __syncthreads();
    for (int j = t; j < n; j += 256) {
        int s = src[e0 + j], d = dst[e0 + j];
        k1[j] = ((u64)d << 38) | ((u64)s << 21) | (u64)(e0 + j);
        atomicAdd(&hist[d >> BKT_SHIFT], 1);
    }
    __syncthreads();
    int v = hist[t];
    runb[t] = v ? atomicAdd(&bcur[t], v) : 0;
    sscan[t] = v;
    __syncthreads();
    for (int off = 1; off < 256; off <<= 1) {
        int x = (t >= off) ? sscan[t - off] : 0;
        __syncthreads();
        sscan[t] += x;
        __syncthreads();
    }
    lbase[t] = sscan[t] - v;
    cur[t] = 0;
    __syncthreads();
    for (int j = t; j < n; j += 256) {
        int b = (int)(k1[j] >> 47);
        int p = lbase[b] + atomicAdd(&cur[b], 1);
        k2[p] = k1[j];
    }
    __syncthreads();
    for (int j = t; j < n; j += 256) {
        int b = (int)(k2[j] >> 47);
        ebuf[runb[b] + (j - lbase[b])] = k2[j];   // coalesced runs
    }
}

// ---- per-bucket CSR: degrees, local scan, LDS scatter, coalesced write ----
__global__ __launch_bounds__(512) void k_csr(const u64* __restrict__ ebuf,
                                             const int* __restrict__ bbase,
                                             int* __restrict__ row_ptr,
                                             int2* __restrict__ adj, int N) {
    __shared__ int deg[BKT_NODES];
    __shared__ int sscan[BKT_NODES];
    __shared__ int cursor[BKT_NODES];
    __shared__ int2 stage[CSR_CAP];
    int b = blockIdx.x, t = threadIdx.x;
    int lo = bbase[b], hi = bbase[b + 1];
    int cnt = hi - lo;
    int node0 = b << BKT_SHIFT;

    deg[t] = 0;
    __syncthreads();
    for (int j = t; j < cnt; j += 512) {
        int d = (int)((ebuf[lo + j] >> 38) & 0x1FFFF);
        atomicAdd(&deg[d - node0], 1);
    }
    __syncthreads();
    int v = deg[t];
    sscan[t] = v;
    __syncthreads();
    for (int off = 1; off < 512; off <<= 1) {
        int x = (t >= off) ? sscan[t - off] : 0;
        __syncthreads();
        sscan[t] += x;
        __syncthreads();
    }
    int ex = sscan[t] - v;
    int node = node0 + t;
    if (node < N) row_ptr[node] = lo + ex;
    cursor[t] = ex;
    __syncthreads();
    for (int j = t; j < cnt; j += 512) {
        u64 key = ebuf[lo + j];
        int d = (int)((key >> 38) & 0x1FFFF) - node0;
        int s = (int)((key >> 21) & 0x1FFFF);
        int eid = (int)(key & 0x1FFFFF);
        int p = atomicAdd(&cursor[d], 1);
        int2 val = make_int2(s, eid);
        if (p < CSR_CAP) stage[p] = val;
        else adj[lo + p] = val;       // overflow fallback (never expected)
    }
    __syncthreads();
    int m = min(cnt, CSR_CAP);
    for (int j = t; j < m; j += 512) adj[lo + j] = stage[j];   // coalesced
}

// ---- ea'[i] = (sum edge_attr over incoming) / deg ----
__global__ void k_agg_ea(const float* __restrict__ ea, const int* __restrict__ row_ptr,
                         const int2* __restrict__ adj, float* __restrict__ out, int N) {
    int wid = threadIdx.x >> 6, lane = threadIdx.x & 63;
    int node = blockIdx.x * 4 + wid;
    if (node >= N) return;
    int q = lane & 3, g = lane >> 2;
    int start = row_ptr[node], end = row_ptr[node + 1];
    float4 acc = {0.f, 0.f, 0.f, 0.f};
    for (int e = start + g; e < end; e += 16) {
        int eid = adj[e].y;
        float4 v = *reinterpret_cast<const float4*>(&ea[(size_t)eid * 16 + q * 4]);
        acc.x += v.x; acc.y += v.y; acc.z += v.z; acc.w += v.w;
    }
#pragma unroll
    for (int m = 4; m <= 32; m <<= 1) {
        acc.x += __shfl_xor(acc.x, m);
        acc.y += __shfl_xor(acc.y, m);
        acc.z += __shfl_xor(acc.z, m);
        acc.w += __shfl_xor(acc.w, m);
    }
    if (lane < 4) {
        float d = (end > start) ? 1.f / (float)(end - start) : 0.f;
        float4 o = {acc.x * d, acc.y * d, acc.z * d, acc.w * d};
        *reinterpret_cast<float4*>(&out[(size_t)node * 16 + q * 4]) = o;
    }
}

// ---- dense GEMM: [S'|Q](Nx128) = [H|ea'](Nx80) @ W80, bias into S' ----
__global__ __launch_bounds__(256) void k_gemm(
    const float* __restrict__ h, const float* __restrict__ eap,
    const float* __restrict__ W, const float* __restrict__ bias,
    float* __restrict__ Sp, float* __restrict__ Q, int N) {
    __shared__ float sInT[80 * 36];
    __shared__ float sW[80 * 128];

    int tid = threadIdx.x;
    int r0 = blockIdx.x * 32;

#pragma unroll
    for (int rep = 0; rep < 2; ++rep) {
        int vid = rep * 256 + tid;
        int i = vid >> 4;
        int j4 = (vid & 15) * 4;
        int row = r0 + i;
        float4 v = (row < N) ? *reinterpret_cast<const float4*>(&h[(size_t)row * 64 + j4])
                             : float4{0.f, 0.f, 0.f, 0.f};
        sInT[(j4 + 0) * 36 + i] = v.x;
        sInT[(j4 + 1) * 36 + i] = v.y;
        sInT[(j4 + 2) * 36 + i] = v.z;
        sInT[(j4 + 3) * 36 + i] = v.w;
    }
    if (tid < 128) {
        int i = tid >> 2;
        int f4 = (tid & 3) * 4;
        int row = r0 + i;
        float4 v = (row < N) ? *reinterpret_cast<const float4*>(&eap[(size_t)row * 16 + f4])
                             : float4{0.f, 0.f, 0.f, 0.f};
        sInT[(64 + f4 + 0) * 36 + i] = v.x;
        sInT[(64 + f4 + 1) * 36 + i] = v.y;
        sInT[(64 + f4 + 2) * 36 + i] = v.z;
        sInT[(64 + f4 + 3) * 36 + i] = v.w;
    }
#pragma unroll
    for (int rep = 0; rep < 10; ++rep) {
        int vid = rep * 256 + tid;
        int k = vid >> 5;
        int c4 = (vid & 31) * 4;
        float4 v;
        if (c4 < 64) {
            const float* s = (k < 64) ? &W[k * 64 + c4] : &W[(128 + k - 64) * 64 + c4];
            v = *reinterpret_cast<const float4*>(s);
        } else {
            if (k < 64) v = *reinterpret_cast<const float4*>(&W[(64 + k) * 64 + (c4 - 64)]);
            else        v = float4{0.f, 0.f, 0.f, 0.f};
        }
        *reinterpret_cast<float4*>(&sW[k * 128 + c4]) = v;
    }
    __syncthreads();

    int rg = tid >> 5, cg = tid & 31;
    int c0 = cg * 4;
    float acc[4][4] = {};
#pragma unroll 8
    for (int k = 0; k < 80; ++k) {
        float4 a = *reinterpret_cast<const float4*>(&sInT[k * 36 + rg * 4]);
        float4 w = *reinterpret_cast<const float4*>(&sW[k * 128 + c0]);
        float av[4] = {a.x, a.y, a.z, a.w};
        float wv[4] = {w.x, w.y, w.z, w.w};
#pragma unroll
        for (int i = 0; i < 4; ++i)
#pragma unroll
            for (int j = 0; j < 4; ++j)
                acc[i][j] = fmaf(av[i], wv[j], acc[i][j]);
    }

    float4 bv = {0.f, 0.f, 0.f, 0.f};
    if (c0 < 64) bv = *reinterpret_cast<const float4*>(&bias[c0]);
#pragma unroll
    for (int i = 0; i < 4; ++i) {
        int row = r0 + rg * 4 + i;
        if (row >= N) continue;
        if (c0 < 64) {
            float4 o = {acc[i][0] + bv.x, acc[i][1] + bv.y, acc[i][2] + bv.z, acc[i][3] + bv.w};
            *reinterpret_cast<float4*>(&Sp[(size_t)row * 64 + c0]) = o;
        } else {
            float4 o = {acc[i][0], acc[i][1], acc[i][2], acc[i][3]};
            *reinterpret_cast<float4*>(&Q[(size_t)row * 64 + (c0 - 64)]) = o;
        }
    }
}

// ---- out[i] = deg(i)*S'[i] + sum_{e:dst=i} Q[src[e]]  (+ReLU) ----
template <bool RELU>
__global__ __launch_bounds__(256) void k_aggregate(
    const float* __restrict__ Sp, const float* __restrict__ Q,
    const int* __restrict__ row_ptr, const int2* __restrict__ adj,
    float* __restrict__ out, int N) {
    int wid = threadIdx.x >> 6, lane = threadIdx.x & 63;
    int node = blockIdx.x * 4 + wid;
    if (node >= N) return;
    int f4 = lane & 15, g = lane >> 4;
    int start = row_ptr[node], end = row_ptr[node + 1];
    float4 acc = {0.f, 0.f, 0.f, 0.f};
    int e = start + g;
    for (; e + 12 < end; e += 16) {
        int s0 = adj[e].x, s1 = adj[e + 4].x, s2 = adj[e + 8].x, s3 = adj[e + 12].x;
        float4 v0 = *reinterpret_cast<const float4*>(&Q[(size_t)s0 * 64 + f4 * 4]);
        float4 v1 = *reinterpret_cast<const float4*>(&Q[(size_t)s1 * 64 + f4 * 4]);
        float4 v2 = *reinterpret_cast<const float4*>(&Q[(size_t)s2 * 64 + f4 * 4]);
        float4 v3 = *reinterpret_cast<const float4*>(&Q[(size_t)s3 * 64 + f4 * 4]);
        acc.x += v0.x + v1.x + v2.x + v3.x;
        acc.y += v0.y + v1.y + v2.y + v3.y;
        acc.z += v0.z + v1.z + v2.z + v3.z;
        acc.w += v0.w + v1.w + v2.w + v3.w;
    }
    for (; e < end; e += 4) {
        int s = adj[e].x;
        float4 v = *reinterpret_cast<const float4*>(&Q[(size_t)s * 64 + f4 * 4]);
        acc.x += v.x; acc.y += v.y; acc.z += v.z; acc.w += v.w;
    }
    acc.x += __shfl_xor(acc.x, 16); acc.y += __shfl_xor(acc.y, 16);
    acc.z += __shfl_xor(acc.z, 16); acc.w += __shfl_xor(acc.w, 16);
    acc.x += __shfl_xor(acc.x, 32); acc.y += __shfl_xor(acc.y, 32);
    acc.z += __shfl_xor(acc.z, 32); acc.w += __shfl_xor(acc.w, 32);
    if (lane < 16) {
        float deg = (float)(end - start);
        float4 s = *reinterpret_cast<const float4*>(&Sp[(size_t)node * 64 + f4 * 4]);
        float4 r = {deg * s.x + acc.x, deg * s.y + acc.y,
                    deg * s.z + acc.z, deg * s.w + acc.w};
        if (RELU) {
            r.x = fmaxf(r.x, 0.f); r.y = fmaxf(r.y, 0.f);
            r.z = fmaxf(r.z, 0.f); r.w = fmaxf(r.w, 0.f);
        }
        *reinterpret_cast<float4*>(&out[(size_t)node * 64 + f4 * 4]) = r;
    }
}

extern "C" void kernel_launch(void* const* d_in, const int* in_sizes, int n_in,
                              void* d_out, int out_size, void* d_ws, size_t ws_size,
                              hipStream_t stream) {
    const float* x  = (const float*)d_in[0];
    const float* ea = (const float*)d_in[1];
    const int* eidx = (const int*)d_in[2];
    const float* W1 = (const float*)d_in[3];
    const float* b1 = (const float*)d_in[4];
    const float* W2 = (const float*)d_in[5];
    const float* b2 = (const float*)d_in[6];
    const float* W3 = (const float*)d_in[7];
    const float* b3 = (const float*)d_in[8];

    int N = in_sizes[0] / 64;
    int E = in_sizes[1] / 16;
    const int* src = eidx;       // edge_index[0]
    const int* dst = eidx + E;   // edge_index[1]
    int NB = (N + BKT_NODES - 1) / BKT_NODES;   // 196 for N=100000 (<=256)

    char* p = (char*)d_ws;
    auto alloc = [&](size_t bytes) {
        char* r = p;
        p += (bytes + 255) & ~(size_t)255;
        return r;
    };
    int*   row_ptr = (int*)alloc((size_t)(N + 1) * 4);
    int*   bcnt    = (int*)alloc(257 * 4);
    int*   bbase   = (int*)alloc(257 * 4);
    int*   bcur    = (int*)alloc(257 * 4);
    int2*  adj     = (int2*)alloc((size_t)E * 8);
    float* eap     = (float*)alloc((size_t)N * 16 * 4);
    float* hbuf    = (float*)alloc((size_t)N * 64 * 4);
    float* Sbuf    = (float*)alloc((size_t)N * 64 * 4);
    float* Qbuf    = (float*)alloc((size_t)N * 64 * 4);
    u64*   ebuf    = (u64*)Qbuf;   // alias: ebuf consumed by k_csr before gemm writes Q

    hipMemsetAsync(bcnt, 0, 257 * 4, stream);

    int gP = (E + PART_EDGES - 1) / PART_EDGES;
    k_hist<<<gP, 256, 0, stream>>>(dst, bcnt, E);
    k_bucket_scan<<<1, 256, 0, stream>>>(bcnt, bbase, bcur, row_ptr, NB, N, E);
    k_part<<<gP, 256, 0, stream>>>(src, dst, bcur, ebuf, E);
    k_csr<<<NB, 512, 0, stream>>>(ebuf, bbase, row_ptr, adj, N);

    int gN4 = (N + 3) / 4;
    k_agg_ea<<<gN4, 256, 0, stream>>>(ea, row_ptr, adj, eap, N);

    int gT = (N + 31) / 32;

    // layer 1: x -> hbuf
    k_gemm<<<gT, 256, 0, stream>>>(x, eap, W1, b1, Sbuf, Qbuf, N);
    k_aggregate<true ><<<gN4, 256, 0, stream>>>(Sbuf, Qbuf, row_ptr, adj, hbuf, N);
    // layer 2: hbuf -> hbuf
    k_gemm<<<gT, 256, 0, stream>>>(hbuf, eap, W2, b2, Sbuf, Qbuf, N);
    k_aggregate<true ><<<gN4, 256, 0, stream>>>(Sbuf, Qbuf, row_ptr, adj, hbuf, N);
    // layer 3: hbuf -> d_out
    k_gemm<<<gT, 256, 0, stream>>>(hbuf, eap, W3, b3, Sbuf, Qbuf, N);
    k_aggregate<false><<<gN4, 256, 0, stream>>>(Sbuf, Qbuf, row_ptr, adj, (float*)d_out, N);
}

// Round 5
// 348.816 us; speedup vs baseline: 1.8975x; 1.1121x over previous
//
#include <hip/hip_runtime.h>
#include <stdint.h>

// EdgeConv, factored twice:
//   out = deg ⊙ (H@Wd + b + (agg_ea/deg)@We) + A·(H@Ws)
//       = deg ⊙ S' + gather_sum(Q),  [S'|Q] = [H|ea'] @ W80  (dense GEMM)
// Q stored bf16 (halves the random-gather bytes); fp32 accumulation.
// CSR build = bucketed counting sort, all scatter contained in LDS.

#define BKT_SHIFT 9
#define BKT_NODES 512
#define PART_EDGES 4096
#define CSR_CAP 12288

typedef unsigned long long u64;
typedef unsigned short u16;

static __device__ __forceinline__ u16 f32_to_bf16(float f) {
    unsigned u = __float_as_uint(f);
    unsigned r = 0x7FFFu + ((u >> 16) & 1u);
    return (u16)((u + r) >> 16);
}
static __device__ __forceinline__ void accum4(float4& a, uint2 q) {
    a.x += __uint_as_float(q.x << 16);
    a.y += __uint_as_float(q.x & 0xFFFF0000u);
    a.z += __uint_as_float(q.y << 16);
    a.w += __uint_as_float(q.y & 0xFFFF0000u);
}

// ---- bucket histogram ----
__global__ __launch_bounds__(256) void k_hist(const int* __restrict__ dst,
                                              int* __restrict__ bcnt, int E) {
    __shared__ int h[256];
    int t = threadIdx.x;
    h[t] = 0;
    __syncthreads();
    int i0 = blockIdx.x * PART_EDGES + t;
#pragma unroll
    for (int k = 0; k < 16; ++k) {
        int i = i0 + k * 256;
        if (i < E) atomicAdd(&h[dst[i] >> BKT_SHIFT], 1);
    }
    __syncthreads();
    int v = h[t];
    if (v) atomicAdd(&bcnt[t], v);
}

// ---- scan bucket counts ----
__global__ __launch_bounds__(256) void k_bucket_scan(const int* __restrict__ bcnt,
                                                     int* __restrict__ bbase,
                                                     int* __restrict__ bcur,
                                                     int* __restrict__ row_ptr,
                                                     int NB, int N, int E) {
    __shared__ int sc[256];
    int t = threadIdx.x;
    int v = (t < NB) ? bcnt[t] : 0;
    sc[t] = v;
    __syncthreads();
    for (int off = 1; off < 256; off <<= 1) {
        int x = (t >= off) ? sc[t - off] : 0;
        __syncthreads();
        sc[t] += x;
        __syncthreads();
    }
    int ex = sc[t] - v;
    if (t < NB) { bbase[t] = ex; bcur[t] = ex; }
    if (t == 0) { bbase[NB] = E; row_ptr[N] = E; }
}

// ---- partition into buckets, coalesced run writes ----
__global__ __launch_bounds__(256) void k_part(const int* __restrict__ src,
                                              const int* __restrict__ dst,
                                              int* __restrict__ bcur,
                                              u64* __restrict__ ebuf, int E) {
    __shared__ u64 k1[PART_EDGES];
    __shared__ u64 k2[PART_EDGES];
    __shared__ int hist[256], sscan[256], lbase[256], runb[256], cur[256];
    int t = threadIdx.x;
    int e0 = blockIdx.x * PART_EDGES;
    int n = min(PART_EDGES, E - e0);

    hist[t] = 0;
    __syncthreads();
    for (int j = t; j < n; j += 256) {
        int s = src[e0 + j], d = dst[e0 + j];
        k1[j] = ((u64)d << 38) | ((u64)s << 21) | (u64)(e0 + j);
        atomicAdd(&hist[d >> BKT_SHIFT], 1);
    }
    __syncthreads();
    int v = hist[t];
    runb[t] = v ? atomicAdd(&bcur[t], v) : 0;
    sscan[t] = v;
    __syncthreads();
    for (int off = 1; off < 256; off <<= 1) {
        int x = (t >= off) ? sscan[t - off] : 0;
        __syncthreads();
        sscan[t] += x;
        __syncthreads();
    }
    lbase[t] = sscan[t] - v;
    cur[t] = 0;
    __syncthreads();
    for (int j = t; j < n; j += 256) {
        int b = (int)(k1[j] >> 47);
        int p = lbase[b] + atomicAdd(&cur[b], 1);
        k2[p] = k1[j];
    }
    __syncthreads();
    for (int j = t; j < n; j += 256) {
        int b = (int)(k2[j] >> 47);
        ebuf[runb[b] + (j - lbase[b])] = k2[j];
    }
}

// ---- per-bucket CSR build; adj split into src / eid streams ----
__global__ __launch_bounds__(512) void k_csr(const u64* __restrict__ ebuf,
                                             const int* __restrict__ bbase,
                                             int* __restrict__ row_ptr,
                                             int* __restrict__ adj_src,
                                             int* __restrict__ adj_eid, int N) {
    __shared__ int deg[BKT_NODES];
    __shared__ int sscan[BKT_NODES];
    __shared__ int cursor[BKT_NODES];
    __shared__ int2 stage[CSR_CAP];
    int b = blockIdx.x, t = threadIdx.x;
    int lo = bbase[b], hi = bbase[b + 1];
    int cnt = hi - lo;
    int node0 = b << BKT_SHIFT;

    deg[t] = 0;
    __syncthreads();
    for (int j = t; j < cnt; j += 512) {
        int d = (int)((ebuf[lo + j] >> 38) & 0x1FFFF);
        atomicAdd(&deg[d - node0], 1);
    }
    __syncthreads();
    int v = deg[t];
    sscan[t] = v;
    __syncthreads();
    for (int off = 1; off < 512; off <<= 1) {
        int x = (t >= off) ? sscan[t - off] : 0;
        __syncthreads();
        sscan[t] += x;
        __syncthreads();
    }
    int ex = sscan[t] - v;
    int node = node0 + t;
    if (node < N) row_ptr[node] = lo + ex;
    cursor[t] = ex;
    __syncthreads();
    for (int j = t; j < cnt; j += 512) {
        u64 key = ebuf[lo + j];
        int d = (int)((key >> 38) & 0x1FFFF) - node0;
        int s = (int)((key >> 21) & 0x1FFFF);
        int eid = (int)(key & 0x1FFFFF);
        int p = atomicAdd(&cursor[d], 1);
        int2 val = make_int2(s, eid);
        if (p < CSR_CAP) stage[p] = val;
        else { adj_src[lo + p] = s; adj_eid[lo + p] = eid; }
    }
    __syncthreads();
    int m = min(cnt, CSR_CAP);
    for (int j = t; j < m; j += 512) {
        adj_src[lo + j] = stage[j].x;
        adj_eid[lo + j] = stage[j].y;
    }
}

// ---- ea'[i] = (sum edge_attr over incoming) / deg ----
__global__ void k_agg_ea(const float* __restrict__ ea, const int* __restrict__ row_ptr,
                         const int* __restrict__ adj_eid, float* __restrict__ out, int N) {
    int wid = threadIdx.x >> 6, lane = threadIdx.x & 63;
    int node = blockIdx.x * 4 + wid;
    if (node >= N) return;
    int q = lane & 3, g = lane >> 2;
    int start = row_ptr[node], end = row_ptr[node + 1];
    float4 acc = {0.f, 0.f, 0.f, 0.f};
    for (int e = start + g; e < end; e += 16) {
        int eid = adj_eid[e];
        float4 v = *reinterpret_cast<const float4*>(&ea[(size_t)eid * 16 + q * 4]);
        acc.x += v.x; acc.y += v.y; acc.z += v.z; acc.w += v.w;
    }
#pragma unroll
    for (int m = 4; m <= 32; m <<= 1) {
        acc.x += __shfl_xor(acc.x, m);
        acc.y += __shfl_xor(acc.y, m);
        acc.z += __shfl_xor(acc.z, m);
        acc.w += __shfl_xor(acc.w, m);
    }
    if (lane < 4) {
        float d = (end > start) ? 1.f / (float)(end - start) : 0.f;
        float4 o = {acc.x * d, acc.y * d, acc.z * d, acc.w * d};
        *reinterpret_cast<float4*>(&out[(size_t)node * 16 + q * 4]) = o;
    }
}

// ---- dense GEMM: Sp fp32, Q bf16 ----
__global__ __launch_bounds__(256) void k_gemm(
    const float* __restrict__ h, const float* __restrict__ eap,
    const float* __restrict__ W, const float* __restrict__ bias,
    float* __restrict__ Sp, u16* __restrict__ Qb, int N) {
    __shared__ float sInT[80 * 36];
    __shared__ float sW[80 * 128];

    int tid = threadIdx.x;
    int r0 = blockIdx.x * 32;

#pragma unroll
    for (int rep = 0; rep < 2; ++rep) {
        int vid = rep * 256 + tid;
        int i = vid >> 4;
        int j4 = (vid & 15) * 4;
        int row = r0 + i;
        float4 v = (row < N) ? *reinterpret_cast<const float4*>(&h[(size_t)row * 64 + j4])
                             : float4{0.f, 0.f, 0.f, 0.f};
        sInT[(j4 + 0) * 36 + i] = v.x;
        sInT[(j4 + 1) * 36 + i] = v.y;
        sInT[(j4 + 2) * 36 + i] = v.z;
        sInT[(j4 + 3) * 36 + i] = v.w;
    }
    if (tid < 128) {
        int i = tid >> 2;
        int f4 = (tid & 3) * 4;
        int row = r0 + i;
        float4 v = (row < N) ? *reinterpret_cast<const float4*>(&eap[(size_t)row * 16 + f4])
                             : float4{0.f, 0.f, 0.f, 0.f};
        sInT[(64 + f4 + 0) * 36 + i] = v.x;
        sInT[(64 + f4 + 1) * 36 + i] = v.y;
        sInT[(64 + f4 + 2) * 36 + i] = v.z;
        sInT[(64 + f4 + 3) * 36 + i] = v.w;
    }
#pragma unroll
    for (int rep = 0; rep < 10; ++rep) {
        int vid = rep * 256 + tid;
        int k = vid >> 5;
        int c4 = (vid & 31) * 4;
        float4 v;
        if (c4 < 64) {
            const float* s = (k < 64) ? &W[k * 64 + c4] : &W[(128 + k - 64) * 64 + c4];
            v = *reinterpret_cast<const float4*>(s);
        } else {
            if (k < 64) v = *reinterpret_cast<const float4*>(&W[(64 + k) * 64 + (c4 - 64)]);
            else        v = float4{0.f, 0.f, 0.f, 0.f};
        }
        *reinterpret_cast<float4*>(&sW[k * 128 + c4]) = v;
    }
    __syncthreads();

    int rg = tid >> 5, cg = tid & 31;
    int c0 = cg * 4;
    float acc[4][4] = {};
#pragma unroll 8
    for (int k = 0; k < 80; ++k) {
        float4 a = *reinterpret_cast<const float4*>(&sInT[k * 36 + rg * 4]);
        float4 w = *reinterpret_cast<const float4*>(&sW[k * 128 + c0]);
        float av[4] = {a.x, a.y, a.z, a.w};
        float wv[4] = {w.x, w.y, w.z, w.w};
#pragma unroll
        for (int i = 0; i < 4; ++i)
#pragma unroll
            for (int j = 0; j < 4; ++j)
                acc[i][j] = fmaf(av[i], wv[j], acc[i][j]);
    }

    float4 bv = {0.f, 0.f, 0.f, 0.f};
    if (c0 < 64) bv = *reinterpret_cast<const float4*>(&bias[c0]);
#pragma unroll
    for (int i = 0; i < 4; ++i) {
        int row = r0 + rg * 4 + i;
        if (row >= N) continue;
        if (c0 < 64) {
            float4 o = {acc[i][0] + bv.x, acc[i][1] + bv.y, acc[i][2] + bv.z, acc[i][3] + bv.w};
            *reinterpret_cast<float4*>(&Sp[(size_t)row * 64 + c0]) = o;
        } else {
            ushort4 o;
            o.x = f32_to_bf16(acc[i][0]);
            o.y = f32_to_bf16(acc[i][1]);
            o.z = f32_to_bf16(acc[i][2]);
            o.w = f32_to_bf16(acc[i][3]);
            *reinterpret_cast<ushort4*>(&Qb[(size_t)row * 64 + (c0 - 64)]) = o;
        }
    }
}

// ---- out[i] = deg(i)*S'[i] + sum Q[src]  (+ReLU); Q bf16 ----
template <bool RELU>
__global__ __launch_bounds__(256) void k_aggregate(
    const float* __restrict__ Sp, const u16* __restrict__ Qb,
    const int* __restrict__ row_ptr, const int* __restrict__ adj_src,
    float* __restrict__ out, int N) {
    int wid = threadIdx.x >> 6, lane = threadIdx.x & 63;
    int node = blockIdx.x * 4 + wid;
    if (node >= N) return;
    int f4 = lane & 15, g = lane >> 4;
    int start = row_ptr[node], end = row_ptr[node + 1];
    float4 acc = {0.f, 0.f, 0.f, 0.f};
    int e = start + g;
    for (; e + 12 < end; e += 16) {
        int s0 = adj_src[e], s1 = adj_src[e + 4], s2 = adj_src[e + 8], s3 = adj_src[e + 12];
        uint2 q0 = *reinterpret_cast<const uint2*>(&Qb[(size_t)s0 * 64 + f4 * 4]);
        uint2 q1 = *reinterpret_cast<const uint2*>(&Qb[(size_t)s1 * 64 + f4 * 4]);
        uint2 q2 = *reinterpret_cast<const uint2*>(&Qb[(size_t)s2 * 64 + f4 * 4]);
        uint2 q3 = *reinterpret_cast<const uint2*>(&Qb[(size_t)s3 * 64 + f4 * 4]);
        accum4(acc, q0); accum4(acc, q1); accum4(acc, q2); accum4(acc, q3);
    }
    for (; e < end; e += 4) {
        int s = adj_src[e];
        uint2 q = *reinterpret_cast<const uint2*>(&Qb[(size_t)s * 64 + f4 * 4]);
        accum4(acc, q);
    }
    acc.x += __shfl_xor(acc.x, 16); acc.y += __shfl_xor(acc.y, 16);
    acc.z += __shfl_xor(acc.z, 16); acc.w += __shfl_xor(acc.w, 16);
    acc.x += __shfl_xor(acc.x, 32); acc.y += __shfl_xor(acc.y, 32);
    acc.z += __shfl_xor(acc.z, 32); acc.w += __shfl_xor(acc.w, 32);
    if (lane < 16) {
        float deg = (float)(end - start);
        float4 s = *reinterpret_cast<const float4*>(&Sp[(size_t)node * 64 + f4 * 4]);
        float4 r = {deg * s.x + acc.x, deg * s.y + acc.y,
                    deg * s.z + acc.z, deg * s.w + acc.w};
        if (RELU) {
            r.x = fmaxf(r.x, 0.f); r.y = fmaxf(r.y, 0.f);
            r.z = fmaxf(r.z, 0.f); r.w = fmaxf(r.w, 0.f);
        }
        *reinterpret_cast<float4*>(&out[(size_t)node * 64 + f4 * 4]) = r;
    }
}

extern "C" void kernel_launch(void* const* d_in, const int* in_sizes, int n_in,
                              void* d_out, int out_size, void* d_ws, size_t ws_size,
                              hipStream_t stream) {
    const float* x  = (const float*)d_in[0];
    const float* ea = (const float*)d_in[1];
    const int* eidx = (const int*)d_in[2];
    const float* W1 = (const float*)d_in[3];
    const float* b1 = (const float*)d_in[4];
    const float* W2 = (const float*)d_in[5];
    const float* b2 = (const float*)d_in[6];
    const float* W3 = (const float*)d_in[7];
    const float* b3 = (const float*)d_in[8];

    int N = in_sizes[0] / 64;
    int E = in_sizes[1] / 16;
    const int* src = eidx;
    const int* dst = eidx + E;
    int NB = (N + BKT_NODES - 1) / BKT_NODES;

    char* p = (char*)d_ws;
    auto alloc = [&](size_t bytes) {
        char* r = p;
        p += (bytes + 255) & ~(size_t)255;
        return r;
    };
    int*   row_ptr = (int*)alloc((size_t)(N + 1) * 4);
    int*   bcnt    = (int*)alloc(257 * 4);
    int*   bbase   = (int*)alloc(257 * 4);
    int*   bcur    = (int*)alloc(257 * 4);
    int*   adj_src = (int*)alloc((size_t)E * 4);
    int*   adj_eid = (int*)alloc((size_t)E * 4);
    float* eap     = (float*)alloc((size_t)N * 16 * 4);
    float* hbuf    = (float*)alloc((size_t)N * 64 * 4);
    float* Sbuf    = (float*)alloc((size_t)N * 64 * 4);
    // Q (bf16, N*64*2 B) unioned with ebuf (E*8 B); ebuf consumed before Q written
    size_t qsz = (size_t)N * 64 * 2, esz = (size_t)E * 8;
    char*  qe      = alloc(qsz > esz ? qsz : esz);
    u16*   Qb      = (u16*)qe;
    u64*   ebuf    = (u64*)qe;

    hipMemsetAsync(bcnt, 0, 257 * 4, stream);

    int gP = (E + PART_EDGES - 1) / PART_EDGES;
    k_hist<<<gP, 256, 0, stream>>>(dst, bcnt, E);
    k_bucket_scan<<<1, 256, 0, stream>>>(bcnt, bbase, bcur, row_ptr, NB, N, E);
    k_part<<<gP, 256, 0, stream>>>(src, dst, bcur, ebuf, E);
    k_csr<<<NB, 512, 0, stream>>>(ebuf, bbase, row_ptr, adj_src, adj_eid, N);

    int gN4 = (N + 3) / 4;
    k_agg_ea<<<gN4, 256, 0, stream>>>(ea, row_ptr, adj_eid, eap, N);

    int gT = (N + 31) / 32;

    k_gemm<<<gT, 256, 0, stream>>>(x, eap, W1, b1, Sbuf, Qb, N);
    k_aggregate<true ><<<gN4, 256, 0, stream>>>(Sbuf, Qb, row_ptr, adj_src, hbuf, N);
    k_gemm<<<gT, 256, 0, stream>>>(hbuf, eap, W2, b2, Sbuf, Qb, N);
    k_aggregate<true ><<<gN4, 256, 0, stream>>>(Sbuf, Qb, row_ptr, adj_src, hbuf, N);
    k_gemm<<<gT, 256, 0, stream>>>(hbuf, eap, W3, b3, Sbuf, Qb, N);
    k_aggregate<false><<<gN4, 256, 0, stream>>>(Sbuf, Qb, row_ptr, adj_src, (float*)d_out, N);
}

// Round 6
// 314.457 us; speedup vs baseline: 2.1048x; 1.1093x over previous
//
#include <hip/hip_runtime.h>
#include <stdint.h>

// EdgeConv, factored twice:
//   out = deg ⊙ (H@Wd + b + (agg_ea/deg)@We) + A·(H@Ws)
//       = deg ⊙ S' + gather_sum(Q),  [S'|Q] = [H|ea'] @ W80  (dense GEMM)
// Q stored bf16; fp32 accumulation. CSR build = bucketed counting sort.
// Gather kernels tuned for MLP: 4 outstanding 16B loads per lane.

#define BKT_SHIFT 9
#define BKT_NODES 512
#define PART_EDGES 4096
#define CSR_CAP 12288

typedef unsigned long long u64;
typedef unsigned short u16;

static __device__ __forceinline__ u16 f32_to_bf16(float f) {
    unsigned u = __float_as_uint(f);
    unsigned r = 0x7FFFu + ((u >> 16) & 1u);
    return (u16)((u + r) >> 16);
}
static __device__ __forceinline__ void accum8(float4& a, float4& b, uint4 q) {
    a.x += __uint_as_float(q.x << 16);
    a.y += __uint_as_float(q.x & 0xFFFF0000u);
    a.z += __uint_as_float(q.y << 16);
    a.w += __uint_as_float(q.y & 0xFFFF0000u);
    b.x += __uint_as_float(q.z << 16);
    b.y += __uint_as_float(q.z & 0xFFFF0000u);
    b.z += __uint_as_float(q.w << 16);
    b.w += __uint_as_float(q.w & 0xFFFF0000u);
}

// ---- bucket histogram ----
__global__ __launch_bounds__(256) void k_hist(const int* __restrict__ dst,
                                              int* __restrict__ bcnt, int E) {
    __shared__ int h[256];
    int t = threadIdx.x;
    h[t] = 0;
    __syncthreads();
    int i0 = blockIdx.x * PART_EDGES + t;
#pragma unroll
    for (int k = 0; k < 16; ++k) {
        int i = i0 + k * 256;
        if (i < E) atomicAdd(&h[dst[i] >> BKT_SHIFT], 1);
    }
    __syncthreads();
    int v = h[t];
    if (v) atomicAdd(&bcnt[t], v);
}

// ---- scan bucket counts ----
__global__ __launch_bounds__(256) void k_bucket_scan(const int* __restrict__ bcnt,
                                                     int* __restrict__ bbase,
                                                     int* __restrict__ bcur,
                                                     int* __restrict__ row_ptr,
                                                     int NB, int N, int E) {
    __shared__ int sc[256];
    int t = threadIdx.x;
    int v = (t < NB) ? bcnt[t] : 0;
    sc[t] = v;
    __syncthreads();
    for (int off = 1; off < 256; off <<= 1) {
        int x = (t >= off) ? sc[t - off] : 0;
        __syncthreads();
        sc[t] += x;
        __syncthreads();
    }
    int ex = sc[t] - v;
    if (t < NB) { bbase[t] = ex; bcur[t] = ex; }
    if (t == 0) { bbase[NB] = E; row_ptr[N] = E; }
}

// ---- partition into buckets, coalesced run writes ----
__global__ __launch_bounds__(256) void k_part(const int* __restrict__ src,
                                              const int* __restrict__ dst,
                                              int* __restrict__ bcur,
                                              u64* __restrict__ ebuf, int E) {
    __shared__ u64 k1[PART_EDGES];
    __shared__ u64 k2[PART_EDGES];
    __shared__ int hist[256], sscan[256], lbase[256], runb[256], cur[256];
    int t = threadIdx.x;
    int e0 = blockIdx.x * PART_EDGES;
    int n = min(PART_EDGES, E - e0);

    hist[t] = 0;
    __syncthreads();
    for (int j = t; j < n; j += 256) {
        int s = src[e0 + j], d = dst[e0 + j];
        k1[j] = ((u64)d << 38) | ((u64)s << 21) | (u64)(e0 + j);
        atomicAdd(&hist[d >> BKT_SHIFT], 1);
    }
    __syncthreads();
    int v = hist[t];
    runb[t] = v ? atomicAdd(&bcur[t], v) : 0;
    sscan[t] = v;
    __syncthreads();
    for (int off = 1; off < 256; off <<= 1) {
        int x = (t >= off) ? sscan[t - off] : 0;
        __syncthreads();
        sscan[t] += x;
        __syncthreads();
    }
    lbase[t] = sscan[t] - v;
    cur[t] = 0;
    __syncthreads();
    for (int j = t; j < n; j += 256) {
        int b = (int)(k1[j] >> 47);
        int p = lbase[b] + atomicAdd(&cur[b], 1);
        k2[p] = k1[j];
    }
    __syncthreads();
    for (int j = t; j < n; j += 256) {
        int b = (int)(k2[j] >> 47);
        ebuf[runb[b] + (j - lbase[b])] = k2[j];
    }
}

// ---- per-bucket CSR build; adj split into src / eid streams ----
__global__ __launch_bounds__(512) void k_csr(const u64* __restrict__ ebuf,
                                             const int* __restrict__ bbase,
                                             int* __restrict__ row_ptr,
                                             int* __restrict__ adj_src,
                                             int* __restrict__ adj_eid, int N) {
    __shared__ int deg[BKT_NODES];
    __shared__ int sscan[BKT_NODES];
    __shared__ int cursor[BKT_NODES];
    __shared__ int2 stage[CSR_CAP];
    int b = blockIdx.x, t = threadIdx.x;
    int lo = bbase[b], hi = bbase[b + 1];
    int cnt = hi - lo;
    int node0 = b << BKT_SHIFT;

    deg[t] = 0;
    __syncthreads();
    for (int j = t; j < cnt; j += 512) {
        int d = (int)((ebuf[lo + j] >> 38) & 0x1FFFF);
        atomicAdd(&deg[d - node0], 1);
    }
    __syncthreads();
    int v = deg[t];
    sscan[t] = v;
    __syncthreads();
    for (int off = 1; off < 512; off <<= 1) {
        int x = (t >= off) ? sscan[t - off] : 0;
        __syncthreads();
        sscan[t] += x;
        __syncthreads();
    }
    int ex = sscan[t] - v;
    int node = node0 + t;
    if (node < N) row_ptr[node] = lo + ex;
    cursor[t] = ex;
    __syncthreads();
    for (int j = t; j < cnt; j += 512) {
        u64 key = ebuf[lo + j];
        int d = (int)((key >> 38) & 0x1FFFF) - node0;
        int s = (int)((key >> 21) & 0x1FFFF);
        int eid = (int)(key & 0x1FFFFF);
        int p = atomicAdd(&cursor[d], 1);
        int2 val = make_int2(s, eid);
        if (p < CSR_CAP) stage[p] = val;
        else { adj_src[lo + p] = s; adj_eid[lo + p] = eid; }
    }
    __syncthreads();
    int m = min(cnt, CSR_CAP);
    for (int j = t; j < m; j += 512) {
        adj_src[lo + j] = stage[j].x;
        adj_eid[lo + j] = stage[j].y;
    }
}

// ---- ea'[i] = (sum edge_attr over incoming) / deg ----
// Wave = 4 nodes; lane = (s:node, r:edge-slot, q:16B chunk); 4-deep unroll
// -> 4 outstanding float4 loads/lane, 64 edges in flight per wave.
__global__ __launch_bounds__(256) void k_agg_ea(
    const float* __restrict__ ea, const int* __restrict__ row_ptr,
    const int* __restrict__ adj_eid, float* __restrict__ out, int N) {
    int wid = threadIdx.x >> 6, lane = threadIdx.x & 63;
    int s = lane >> 4, r = (lane >> 2) & 3, q = lane & 3;
    int node = blockIdx.x * 16 + wid * 4 + s;
    if (node >= N) return;
    int start = row_ptr[node], end = row_ptr[node + 1];
    float4 acc = {0.f, 0.f, 0.f, 0.f};
    int e = start + r;
    for (; e + 12 < end; e += 16) {
        int i0 = adj_eid[e], i1 = adj_eid[e + 4], i2 = adj_eid[e + 8], i3 = adj_eid[e + 12];
        float4 v0 = *reinterpret_cast<const float4*>(&ea[(size_t)i0 * 16 + q * 4]);
        float4 v1 = *reinterpret_cast<const float4*>(&ea[(size_t)i1 * 16 + q * 4]);
        float4 v2 = *reinterpret_cast<const float4*>(&ea[(size_t)i2 * 16 + q * 4]);
        float4 v3 = *reinterpret_cast<const float4*>(&ea[(size_t)i3 * 16 + q * 4]);
        acc.x += v0.x + v1.x + v2.x + v3.x;
        acc.y += v0.y + v1.y + v2.y + v3.y;
        acc.z += v0.z + v1.z + v2.z + v3.z;
        acc.w += v0.w + v1.w + v2.w + v3.w;
    }
    for (; e < end; e += 4) {
        int i = adj_eid[e];
        float4 v = *reinterpret_cast<const float4*>(&ea[(size_t)i * 16 + q * 4]);
        acc.x += v.x; acc.y += v.y; acc.z += v.z; acc.w += v.w;
    }
    acc.x += __shfl_xor(acc.x, 4); acc.y += __shfl_xor(acc.y, 4);
    acc.z += __shfl_xor(acc.z, 4); acc.w += __shfl_xor(acc.w, 4);
    acc.x += __shfl_xor(acc.x, 8); acc.y += __shfl_xor(acc.y, 8);
    acc.z += __shfl_xor(acc.z, 8); acc.w += __shfl_xor(acc.w, 8);
    if (r == 0) {
        float d = (end > start) ? 1.f / (float)(end - start) : 0.f;
        float4 o = {acc.x * d, acc.y * d, acc.z * d, acc.w * d};
        *reinterpret_cast<float4*>(&out[(size_t)node * 16 + q * 4]) = o;
    }
}

// ---- dense GEMM: Sp fp32, Q bf16 ----
__global__ __launch_bounds__(256) void k_gemm(
    const float* __restrict__ h, const float* __restrict__ eap,
    const float* __restrict__ W, const float* __restrict__ bias,
    float* __restrict__ Sp, u16* __restrict__ Qb, int N) {
    __shared__ float sInT[80 * 36];
    __shared__ float sW[80 * 128];

    int tid = threadIdx.x;
    int r0 = blockIdx.x * 32;

#pragma unroll
    for (int rep = 0; rep < 2; ++rep) {
        int vid = rep * 256 + tid;
        int i = vid >> 4;
        int j4 = (vid & 15) * 4;
        int row = r0 + i;
        float4 v = (row < N) ? *reinterpret_cast<const float4*>(&h[(size_t)row * 64 + j4])
                             : float4{0.f, 0.f, 0.f, 0.f};
        sInT[(j4 + 0) * 36 + i] = v.x;
        sInT[(j4 + 1) * 36 + i] = v.y;
        sInT[(j4 + 2) * 36 + i] = v.z;
        sInT[(j4 + 3) * 36 + i] = v.w;
    }
    if (tid < 128) {
        int i = tid >> 2;
        int f4 = (tid & 3) * 4;
        int row = r0 + i;
        float4 v = (row < N) ? *reinterpret_cast<const float4*>(&eap[(size_t)row * 16 + f4])
                             : float4{0.f, 0.f, 0.f, 0.f};
        sInT[(64 + f4 + 0) * 36 + i] = v.x;
        sInT[(64 + f4 + 1) * 36 + i] = v.y;
        sInT[(64 + f4 + 2) * 36 + i] = v.z;
        sInT[(64 + f4 + 3) * 36 + i] = v.w;
    }
#pragma unroll
    for (int rep = 0; rep < 10; ++rep) {
        int vid = rep * 256 + tid;
        int k = vid >> 5;
        int c4 = (vid & 31) * 4;
        float4 v;
        if (c4 < 64) {
            const float* s = (k < 64) ? &W[k * 64 + c4] : &W[(128 + k - 64) * 64 + c4];
            v = *reinterpret_cast<const float4*>(s);
        } else {
            if (k < 64) v = *reinterpret_cast<const float4*>(&W[(64 + k) * 64 + (c4 - 64)]);
            else        v = float4{0.f, 0.f, 0.f, 0.f};
        }
        *reinterpret_cast<float4*>(&sW[k * 128 + c4]) = v;
    }
    __syncthreads();

    int rg = tid >> 5, cg = tid & 31;
    int c0 = cg * 4;
    float acc[4][4] = {};
#pragma unroll 8
    for (int k = 0; k < 80; ++k) {
        float4 a = *reinterpret_cast<const float4*>(&sInT[k * 36 + rg * 4]);
        float4 w = *reinterpret_cast<const float4*>(&sW[k * 128 + c0]);
        float av[4] = {a.x, a.y, a.z, a.w};
        float wv[4] = {w.x, w.y, w.z, w.w};
#pragma unroll
        for (int i = 0; i < 4; ++i)
#pragma unroll
            for (int j = 0; j < 4; ++j)
                acc[i][j] = fmaf(av[i], wv[j], acc[i][j]);
    }

    float4 bv = {0.f, 0.f, 0.f, 0.f};
    if (c0 < 64) bv = *reinterpret_cast<const float4*>(&bias[c0]);
#pragma unroll
    for (int i = 0; i < 4; ++i) {
        int row = r0 + rg * 4 + i;
        if (row >= N) continue;
        if (c0 < 64) {
            float4 o = {acc[i][0] + bv.x, acc[i][1] + bv.y, acc[i][2] + bv.z, acc[i][3] + bv.w};
            *reinterpret_cast<float4*>(&Sp[(size_t)row * 64 + c0]) = o;
        } else {
            ushort4 o;
            o.x = f32_to_bf16(acc[i][0]);
            o.y = f32_to_bf16(acc[i][1]);
            o.z = f32_to_bf16(acc[i][2]);
            o.w = f32_to_bf16(acc[i][3]);
            *reinterpret_cast<ushort4*>(&Qb[(size_t)row * 64 + (c0 - 64)]) = o;
        }
    }
}

// ---- out[i] = deg(i)*S'[i] + sum Q[src]  (+ReLU); Q bf16 ----
// Wave = 2 nodes; lane = (s:node, r:edge-slot(4), c:16B chunk(8)); 4-deep
// unroll -> 4 outstanding uint4 loads/lane, 32 edges in flight per wave.
template <bool RELU>
__global__ __launch_bounds__(256) void k_aggregate(
    const float* __restrict__ Sp, const u16* __restrict__ Qb,
    const int* __restrict__ row_ptr, const int* __restrict__ adj_src,
    float* __restrict__ out, int N) {
    int wid = threadIdx.x >> 6, lane = threadIdx.x & 63;
    int s = lane >> 5, r = (lane >> 3) & 3, c = lane & 7;
    int node = blockIdx.x * 8 + wid * 2 + s;
    if (node >= N) return;
    int start = row_ptr[node], end = row_ptr[node + 1];
    float4 a0 = {0.f, 0.f, 0.f, 0.f}, a1 = {0.f, 0.f, 0.f, 0.f};
    int e = start + r;
    for (; e + 12 < end; e += 16) {
        int s0 = adj_src[e], s1 = adj_src[e + 4], s2 = adj_src[e + 8], s3 = adj_src[e + 12];
        uint4 q0 = *reinterpret_cast<const uint4*>(&Qb[(size_t)s0 * 64 + c * 8]);
        uint4 q1 = *reinterpret_cast<const uint4*>(&Qb[(size_t)s1 * 64 + c * 8]);
        uint4 q2 = *reinterpret_cast<const uint4*>(&Qb[(size_t)s2 * 64 + c * 8]);
        uint4 q3 = *reinterpret_cast<const uint4*>(&Qb[(size_t)s3 * 64 + c * 8]);
        accum8(a0, a1, q0); accum8(a0, a1, q1); accum8(a0, a1, q2); accum8(a0, a1, q3);
    }
    for (; e < end; e += 4) {
        int sv = adj_src[e];
        uint4 q = *reinterpret_cast<const uint4*>(&Qb[(size_t)sv * 64 + c * 8]);
        accum8(a0, a1, q);
    }
#pragma unroll
    for (int m = 8; m <= 16; m <<= 1) {
        a0.x += __shfl_xor(a0.x, m); a0.y += __shfl_xor(a0.y, m);
        a0.z += __shfl_xor(a0.z, m); a0.w += __shfl_xor(a0.w, m);
        a1.x += __shfl_xor(a1.x, m); a1.y += __shfl_xor(a1.y, m);
        a1.z += __shfl_xor(a1.z, m); a1.w += __shfl_xor(a1.w, m);
    }
    if (r == 0) {
        float deg = (float)(end - start);
        float4 s0 = *reinterpret_cast<const float4*>(&Sp[(size_t)node * 64 + c * 8]);
        float4 s1 = *reinterpret_cast<const float4*>(&Sp[(size_t)node * 64 + c * 8 + 4]);
        float4 r0 = {deg * s0.x + a0.x, deg * s0.y + a0.y, deg * s0.z + a0.z, deg * s0.w + a0.w};
        float4 r1 = {deg * s1.x + a1.x, deg * s1.y + a1.y, deg * s1.z + a1.z, deg * s1.w + a1.w};
        if (RELU) {
            r0.x = fmaxf(r0.x, 0.f); r0.y = fmaxf(r0.y, 0.f);
            r0.z = fmaxf(r0.z, 0.f); r0.w = fmaxf(r0.w, 0.f);
            r1.x = fmaxf(r1.x, 0.f); r1.y = fmaxf(r1.y, 0.f);
            r1.z = fmaxf(r1.z, 0.f); r1.w = fmaxf(r1.w, 0.f);
        }
        *reinterpret_cast<float4*>(&out[(size_t)node * 64 + c * 8]) = r0;
        *reinterpret_cast<float4*>(&out[(size_t)node * 64 + c * 8 + 4]) = r1;
    }
}

extern "C" void kernel_launch(void* const* d_in, const int* in_sizes, int n_in,
                              void* d_out, int out_size, void* d_ws, size_t ws_size,
                              hipStream_t stream) {
    const float* x  = (const float*)d_in[0];
    const float* ea = (const float*)d_in[1];
    const int* eidx = (const int*)d_in[2];
    const float* W1 = (const float*)d_in[3];
    const float* b1 = (const float*)d_in[4];
    const float* W2 = (const float*)d_in[5];
    const float* b2 = (const float*)d_in[6];
    const float* W3 = (const float*)d_in[7];
    const float* b3 = (const float*)d_in[8];

    int N = in_sizes[0] / 64;
    int E = in_sizes[1] / 16;
    const int* src = eidx;
    const int* dst = eidx + E;
    int NB = (N + BKT_NODES - 1) / BKT_NODES;

    char* p = (char*)d_ws;
    auto alloc = [&](size_t bytes) {
        char* r = p;
        p += (bytes + 255) & ~(size_t)255;
        return r;
    };
    int*   row_ptr = (int*)alloc((size_t)(N + 1) * 4);
    int*   bcnt    = (int*)alloc(257 * 4);
    int*   bbase   = (int*)alloc(257 * 4);
    int*   bcur    = (int*)alloc(257 * 4);
    int*   adj_src = (int*)alloc((size_t)E * 4);
    int*   adj_eid = (int*)alloc((size_t)E * 4);
    float* eap     = (float*)alloc((size_t)N * 16 * 4);
    float* hbuf    = (float*)alloc((size_t)N * 64 * 4);
    float* Sbuf    = (float*)alloc((size_t)N * 64 * 4);
    size_t qsz = (size_t)N * 64 * 2, esz = (size_t)E * 8;
    char*  qe      = alloc(qsz > esz ? qsz : esz);
    u16*   Qb      = (u16*)qe;
    u64*   ebuf    = (u64*)qe;   // alias: consumed by k_csr before Q written

    hipMemsetAsync(bcnt, 0, 257 * 4, stream);

    int gP = (E + PART_EDGES - 1) / PART_EDGES;
    k_hist<<<gP, 256, 0, stream>>>(dst, bcnt, E);
    k_bucket_scan<<<1, 256, 0, stream>>>(bcnt, bbase, bcur, row_ptr, NB, N, E);
    k_part<<<gP, 256, 0, stream>>>(src, dst, bcur, ebuf, E);
    k_csr<<<NB, 512, 0, stream>>>(ebuf, bbase, row_ptr, adj_src, adj_eid, N);

    k_agg_ea<<<(N + 15) / 16, 256, 0, stream>>>(ea, row_ptr, adj_eid, eap, N);

    int gT = (N + 31) / 32;
    int gA = (N + 7) / 8;

    k_gemm<<<gT, 256, 0, stream>>>(x, eap, W1, b1, Sbuf, Qb, N);
    k_aggregate<true ><<<gA, 256, 0, stream>>>(Sbuf, Qb, row_ptr, adj_src, hbuf, N);
    k_gemm<<<gT, 256, 0, stream>>>(hbuf, eap, W2, b2, Sbuf, Qb, N);
    k_aggregate<true ><<<gA, 256, 0, stream>>>(Sbuf, Qb, row_ptr, adj_src, hbuf, N);
    k_gemm<<<gT, 256, 0, stream>>>(hbuf, eap, W3, b3, Sbuf, Qb, N);
    k_aggregate<false><<<gA, 256, 0, stream>>>(Sbuf, Qb, row_ptr, adj_src, (float*)d_out, N);
}

// Round 7
// 283.270 us; speedup vs baseline: 2.3365x; 1.1101x over previous
//
#include <hip/hip_runtime.h>
#include <stdint.h>

// EdgeConv, factored twice:
//   out = deg ⊙ (H@Wd + b + (agg_ea/deg)@We) + A·(H@Ws)
//       = deg ⊙ S' + gather_sum(Q),  [S'|Q] = [H|ea'] @ W80
// GEMM now bf16 MFMA (16x16x32), K padded 80->96. h/Sp/Q/ea' all bf16
// (fp32 accumulation everywhere); only d_out fp32. CSR build via bucketed
// counting sort (all random scatter in LDS).

#define BKT_SHIFT 9
#define BKT_NODES 512
#define PART_EDGES 4096
#define CSR_CAP 12288
#define PADK 104            // LDS row stride in bf16 (96 used + 8 pad)

typedef unsigned long long u64;
typedef unsigned short u16;
typedef __attribute__((ext_vector_type(8))) short short8v;  // 8 bf16
typedef __attribute__((ext_vector_type(4))) float f32x4;

static __device__ __forceinline__ u16 f32_to_bf16(float f) {
    unsigned u = __float_as_uint(f);
    unsigned r = 0x7FFFu + ((u >> 16) & 1u);
    return (u16)((u + r) >> 16);
}
static __device__ __forceinline__ void accum8(float4& a, float4& b, uint4 q) {
    a.x += __uint_as_float(q.x << 16);
    a.y += __uint_as_float(q.x & 0xFFFF0000u);
    a.z += __uint_as_float(q.y << 16);
    a.w += __uint_as_float(q.y & 0xFFFF0000u);
    b.x += __uint_as_float(q.z << 16);
    b.y += __uint_as_float(q.z & 0xFFFF0000u);
    b.z += __uint_as_float(q.w << 16);
    b.w += __uint_as_float(q.w & 0xFFFF0000u);
}

// ---- bucket histogram ----
__global__ __launch_bounds__(256) void k_hist(const int* __restrict__ dst,
                                              int* __restrict__ bcnt, int E) {
    __shared__ int h[256];
    int t = threadIdx.x;
    h[t] = 0;
    __syncthreads();
    int i0 = blockIdx.x * PART_EDGES + t;
#pragma unroll
    for (int k = 0; k < 16; ++k) {
        int i = i0 + k * 256;
        if (i < E) atomicAdd(&h[dst[i] >> BKT_SHIFT], 1);
    }
    __syncthreads();
    int v = h[t];
    if (v) atomicAdd(&bcnt[t], v);
}

// ---- scan bucket counts ----
__global__ __launch_bounds__(256) void k_bucket_scan(const int* __restrict__ bcnt,
                                                     int* __restrict__ bbase,
                                                     int* __restrict__ bcur,
                                                     int* __restrict__ row_ptr,
                                                     int NB, int N, int E) {
    __shared__ int sc[256];
    int t = threadIdx.x;
    int v = (t < NB) ? bcnt[t] : 0;
    sc[t] = v;
    __syncthreads();
    for (int off = 1; off < 256; off <<= 1) {
        int x = (t >= off) ? sc[t - off] : 0;
        __syncthreads();
        sc[t] += x;
        __syncthreads();
    }
    int ex = sc[t] - v;
    if (t < NB) { bbase[t] = ex; bcur[t] = ex; }
    if (t == 0) { bbase[NB] = E; row_ptr[N] = E; }
}

// ---- partition into buckets, coalesced run writes ----
__global__ __launch_bounds__(256) void k_part(const int* __restrict__ src,
                                              const int* __restrict__ dst,
                                              int* __restrict__ bcur,
                                              u64* __restrict__ ebuf, int E) {
    __shared__ u64 k1[PART_EDGES];
    __shared__ u64 k2[PART_EDGES];
    __shared__ int hist[256], sscan[256], lbase[256], runb[256], cur[256];
    int t = threadIdx.x;
    int e0 = blockIdx.x * PART_EDGES;
    int n = min(PART_EDGES, E - e0);

    hist[t] = 0;
    __syncthreads();
    for (int j = t; j < n; j += 256) {
        int s = src[e0 + j], d = dst[e0 + j];
        k1[j] = ((u64)d << 38) | ((u64)s << 21) | (u64)(e0 + j);
        atomicAdd(&hist[d >> BKT_SHIFT], 1);
    }
    __syncthreads();
    int v = hist[t];
    runb[t] = v ? atomicAdd(&bcur[t], v) : 0;
    sscan[t] = v;
    __syncthreads();
    for (int off = 1; off < 256; off <<= 1) {
        int x = (t >= off) ? sscan[t - off] : 0;
        __syncthreads();
        sscan[t] += x;
        __syncthreads();
    }
    lbase[t] = sscan[t] - v;
    cur[t] = 0;
    __syncthreads();
    for (int j = t; j < n; j += 256) {
        int b = (int)(k1[j] >> 47);
        int p = lbase[b] + atomicAdd(&cur[b], 1);
        k2[p] = k1[j];
    }
    __syncthreads();
    for (int j = t; j < n; j += 256) {
        int b = (int)(k2[j] >> 47);
        ebuf[runb[b] + (j - lbase[b])] = k2[j];
    }
}

// ---- per-bucket CSR build ----
__global__ __launch_bounds__(512) void k_csr(const u64* __restrict__ ebuf,
                                             const int* __restrict__ bbase,
                                             int* __restrict__ row_ptr,
                                             int* __restrict__ adj_src,
                                             int* __restrict__ adj_eid, int N) {
    __shared__ int deg[BKT_NODES];
    __shared__ int sscan[BKT_NODES];
    __shared__ int cursor[BKT_NODES];
    __shared__ int2 stage[CSR_CAP];
    int b = blockIdx.x, t = threadIdx.x;
    int lo = bbase[b], hi = bbase[b + 1];
    int cnt = hi - lo;
    int node0 = b << BKT_SHIFT;

    deg[t] = 0;
    __syncthreads();
    for (int j = t; j < cnt; j += 512) {
        int d = (int)((ebuf[lo + j] >> 38) & 0x1FFFF);
        atomicAdd(&deg[d - node0], 1);
    }
    __syncthreads();
    int v = deg[t];
    sscan[t] = v;
    __syncthreads();
    for (int off = 1; off < 512; off <<= 1) {
        int x = (t >= off) ? sscan[t - off] : 0;
        __syncthreads();
        sscan[t] += x;
        __syncthreads();
    }
    int ex = sscan[t] - v;
    int node = node0 + t;
    if (node < N) row_ptr[node] = lo + ex;
    cursor[t] = ex;
    __syncthreads();
    for (int j = t; j < cnt; j += 512) {
        u64 key = ebuf[lo + j];
        int d = (int)((key >> 38) & 0x1FFFF) - node0;
        int s = (int)((key >> 21) & 0x1FFFF);
        int eid = (int)(key & 0x1FFFFF);
        int p = atomicAdd(&cursor[d], 1);
        int2 val = make_int2(s, eid);
        if (p < CSR_CAP) stage[p] = val;
        else { adj_src[lo + p] = s; adj_eid[lo + p] = eid; }
    }
    __syncthreads();
    int m = min(cnt, CSR_CAP);
    for (int j = t; j < m; j += 512) {
        adj_src[lo + j] = stage[j].x;
        adj_eid[lo + j] = stage[j].y;
    }
}

// ---- ea'[i] = (sum edge_attr over incoming)/deg, output bf16 ----
__global__ __launch_bounds__(256) void k_agg_ea(
    const float* __restrict__ ea, const int* __restrict__ row_ptr,
    const int* __restrict__ adj_eid, u16* __restrict__ out, int N) {
    int wid = threadIdx.x >> 6, lane = threadIdx.x & 63;
    int s = lane >> 4, r = (lane >> 2) & 3, q = lane & 3;
    int node = blockIdx.x * 16 + wid * 4 + s;
    if (node >= N) return;
    int start = row_ptr[node], end = row_ptr[node + 1];
    float4 acc = {0.f, 0.f, 0.f, 0.f};
    int e = start + r;
    for (; e + 12 < end; e += 16) {
        int i0 = adj_eid[e], i1 = adj_eid[e + 4], i2 = adj_eid[e + 8], i3 = adj_eid[e + 12];
        float4 v0 = *reinterpret_cast<const float4*>(&ea[(size_t)i0 * 16 + q * 4]);
        float4 v1 = *reinterpret_cast<const float4*>(&ea[(size_t)i1 * 16 + q * 4]);
        float4 v2 = *reinterpret_cast<const float4*>(&ea[(size_t)i2 * 16 + q * 4]);
        float4 v3 = *reinterpret_cast<const float4*>(&ea[(size_t)i3 * 16 + q * 4]);
        acc.x += v0.x + v1.x + v2.x + v3.x;
        acc.y += v0.y + v1.y + v2.y + v3.y;
        acc.z += v0.z + v1.z + v2.z + v3.z;
        acc.w += v0.w + v1.w + v2.w + v3.w;
    }
    for (; e < end; e += 4) {
        int i = adj_eid[e];
        float4 v = *reinterpret_cast<const float4*>(&ea[(size_t)i * 16 + q * 4]);
        acc.x += v.x; acc.y += v.y; acc.z += v.z; acc.w += v.w;
    }
    acc.x += __shfl_xor(acc.x, 4); acc.y += __shfl_xor(acc.y, 4);
    acc.z += __shfl_xor(acc.z, 4); acc.w += __shfl_xor(acc.w, 4);
    acc.x += __shfl_xor(acc.x, 8); acc.y += __shfl_xor(acc.y, 8);
    acc.z += __shfl_xor(acc.z, 8); acc.w += __shfl_xor(acc.w, 8);
    if (r == 0) {
        float d = (end > start) ? 1.f / (float)(end - start) : 0.f;
        ushort4 o = { f32_to_bf16(acc.x * d), f32_to_bf16(acc.y * d),
                      f32_to_bf16(acc.z * d), f32_to_bf16(acc.w * d) };
        *reinterpret_cast<ushort4*>(&out[(size_t)node * 16 + q * 4]) = o;
    }
}

// ---- prep: Wt[layer][col][k] bf16, W80 row remap, K padded 80->96(->104) ----
__global__ __launch_bounds__(256) void k_prep_w(const float* __restrict__ W1,
                                                const float* __restrict__ W2,
                                                const float* __restrict__ W3,
                                                u16* __restrict__ wt) {
    const float* W = (blockIdx.x == 0) ? W1 : (blockIdx.x == 1) ? W2 : W3;
    u16* o = wt + (size_t)blockIdx.x * 128 * PADK;
    for (int idx = threadIdx.x; idx < 128 * PADK; idx += 256) {
        int c = idx / PADK, k = idx % PADK;
        float v = 0.f;
        if (c < 64) {
            if (k < 64) v = W[k * 64 + c];
            else if (k < 80) v = W[(128 + k - 64) * 64 + c];
        } else {
            if (k < 64) v = W[(64 + k) * 64 + (c - 64)];
        }
        o[idx] = f32_to_bf16(v);
    }
}

// ---- MFMA GEMM: [S'|Q](Nx128) = [H|ea'](Nx96pad) @ W80; Sp,Q bf16 out ----
// Tile 32 rows x 128 cols, 4 waves, each wave: 2 row x 4 col 16x16 tiles? ->
// wave w: row-tile rt=w&1, col-quad cq=w>>1 (4 tiles), 12 MFMA (K=96).
template <int FP32IN>
__global__ __launch_bounds__(256) void k_gemm_mfma(
    const void* __restrict__ hin, const u16* __restrict__ eapb,
    const u16* __restrict__ wt, const float* __restrict__ bias,
    u16* __restrict__ Spb, u16* __restrict__ Qb, int N) {
    __shared__ __align__(16) u16 sIn[32 * PADK];
    __shared__ __align__(16) u16 sWt[128 * PADK];
    int tid = threadIdx.x;
    int r0 = blockIdx.x * 32;

    // stage Wt: 128*PADK*2 B = 1664 uint4
    for (int i = tid; i < 128 * PADK / 8; i += 256)
        reinterpret_cast<uint4*>(sWt)[i] = reinterpret_cast<const uint4*>(wt)[i];

    // stage input rows (k 0..63)
    if (FP32IN) {
        const float* h = (const float*)hin;
#pragma unroll
        for (int p2 = 0; p2 < 2; ++p2) {
            int row = p2 * 16 + (tid >> 4);
            int c4 = (tid & 15) * 4;
            int gr = r0 + row;
            float4 v = (gr < N) ? *reinterpret_cast<const float4*>(&h[(size_t)gr * 64 + c4])
                                : float4{0.f, 0.f, 0.f, 0.f};
            ushort4 o = { f32_to_bf16(v.x), f32_to_bf16(v.y),
                          f32_to_bf16(v.z), f32_to_bf16(v.w) };
            *reinterpret_cast<ushort4*>(&sIn[row * PADK + c4]) = o;
        }
    } else {
        const u16* h = (const u16*)hin;
        int row = tid >> 3;
        int c8 = (tid & 7) * 8;
        int gr = r0 + row;
        uint4 v = (gr < N) ? *reinterpret_cast<const uint4*>(&h[(size_t)gr * 64 + c8])
                           : uint4{0u, 0u, 0u, 0u};
        *reinterpret_cast<uint4*>(&sIn[row * PADK + c8]) = v;
    }
    // ea' (k 64..79)
    if (tid < 64) {
        int row = tid >> 1;
        int c8 = (tid & 1) * 8;
        int gr = r0 + row;
        uint4 v = (gr < N) ? *reinterpret_cast<const uint4*>(&eapb[(size_t)gr * 16 + c8])
                           : uint4{0u, 0u, 0u, 0u};
        *reinterpret_cast<uint4*>(&sIn[row * PADK + 64 + c8]) = v;
    }
    // zero pad (k 80..95)
    if (tid < 128) {
        int row = tid >> 2;
        int c4 = (tid & 3) * 4;
        ushort4 z = {0, 0, 0, 0};
        *reinterpret_cast<ushort4*>(&sIn[row * PADK + 80 + c4]) = z;
    }
    __syncthreads();

    int wv = tid >> 6, lane = tid & 63;
    int rt = wv & 1, cq = wv >> 1;
    int lrow = lane & 15, lk = (lane >> 4) * 8;

    f32x4 acc[4] = {{0.f,0.f,0.f,0.f},{0.f,0.f,0.f,0.f},{0.f,0.f,0.f,0.f},{0.f,0.f,0.f,0.f}};
#pragma unroll
    for (int kk = 0; kk < 3; ++kk) {
        short8v a = *reinterpret_cast<const short8v*>(&sIn[(rt * 16 + lrow) * PADK + kk * 32 + lk]);
#pragma unroll
        for (int j = 0; j < 4; ++j) {
            int c0 = (cq * 4 + j) * 16;
            short8v b = *reinterpret_cast<const short8v*>(&sWt[(c0 + lrow) * PADK + kk * 32 + lk]);
            acc[j] = __builtin_amdgcn_mfma_f32_16x16x32_bf16(a, b, acc[j], 0, 0, 0);
        }
    }

    int orow0 = rt * 16 + (lane >> 4) * 4;
#pragma unroll
    for (int j = 0; j < 4; ++j) {
        int col = (cq * 4 + j) * 16 + lrow;
        float bv = (col < 64) ? bias[col] : 0.f;
#pragma unroll
        for (int i = 0; i < 4; ++i) {
            int grow = r0 + orow0 + i;
            if (grow >= N) continue;
            float v = acc[j][i];
            if (col < 64) Spb[(size_t)grow * 64 + col] = f32_to_bf16(v + bv);
            else          Qb[(size_t)grow * 64 + (col - 64)] = f32_to_bf16(v);
        }
    }
}

// ---- out[i] = deg(i)*S'[i] + sum Q[src]  (+ReLU); Sp/Q bf16 in ----
template <bool RELU, bool F32OUT>
__global__ __launch_bounds__(256) void k_aggregate(
    const u16* __restrict__ Spb, const u16* __restrict__ Qb,
    const int* __restrict__ row_ptr, const int* __restrict__ adj_src,
    void* __restrict__ out, int N) {
    int wid = threadIdx.x >> 6, lane = threadIdx.x & 63;
    int s = lane >> 5, r = (lane >> 3) & 3, c = lane & 7;
    int node = blockIdx.x * 8 + wid * 2 + s;
    if (node >= N) return;
    int start = row_ptr[node], end = row_ptr[node + 1];
    float4 a0 = {0.f, 0.f, 0.f, 0.f}, a1 = {0.f, 0.f, 0.f, 0.f};
    int e = start + r;
    for (; e + 12 < end; e += 16) {
        int s0 = adj_src[e], s1 = adj_src[e + 4], s2 = adj_src[e + 8], s3 = adj_src[e + 12];
        uint4 q0 = *reinterpret_cast<const uint4*>(&Qb[(size_t)s0 * 64 + c * 8]);
        uint4 q1 = *reinterpret_cast<const uint4*>(&Qb[(size_t)s1 * 64 + c * 8]);
        uint4 q2 = *reinterpret_cast<const uint4*>(&Qb[(size_t)s2 * 64 + c * 8]);
        uint4 q3 = *reinterpret_cast<const uint4*>(&Qb[(size_t)s3 * 64 + c * 8]);
        accum8(a0, a1, q0); accum8(a0, a1, q1); accum8(a0, a1, q2); accum8(a0, a1, q3);
    }
    for (; e < end; e += 4) {
        int sv = adj_src[e];
        uint4 q = *reinterpret_cast<const uint4*>(&Qb[(size_t)sv * 64 + c * 8]);
        accum8(a0, a1, q);
    }
#pragma unroll
    for (int m = 8; m <= 16; m <<= 1) {
        a0.x += __shfl_xor(a0.x, m); a0.y += __shfl_xor(a0.y, m);
        a0.z += __shfl_xor(a0.z, m); a0.w += __shfl_xor(a0.w, m);
        a1.x += __shfl_xor(a1.x, m); a1.y += __shfl_xor(a1.y, m);
        a1.z += __shfl_xor(a1.z, m); a1.w += __shfl_xor(a1.w, m);
    }
    if (r == 0) {
        float deg = (float)(end - start);
        uint4 spq = *reinterpret_cast<const uint4*>(&Spb[(size_t)node * 64 + c * 8]);
        float4 s0 = {0.f,0.f,0.f,0.f}, s1 = {0.f,0.f,0.f,0.f};
        accum8(s0, s1, spq);
        float4 r0 = {deg * s0.x + a0.x, deg * s0.y + a0.y, deg * s0.z + a0.z, deg * s0.w + a0.w};
        float4 r1 = {deg * s1.x + a1.x, deg * s1.y + a1.y, deg * s1.z + a1.z, deg * s1.w + a1.w};
        if (RELU) {
            r0.x = fmaxf(r0.x, 0.f); r0.y = fmaxf(r0.y, 0.f);
            r0.z = fmaxf(r0.z, 0.f); r0.w = fmaxf(r0.w, 0.f);
            r1.x = fmaxf(r1.x, 0.f); r1.y = fmaxf(r1.y, 0.f);
            r1.z = fmaxf(r1.z, 0.f); r1.w = fmaxf(r1.w, 0.f);
        }
        if (F32OUT) {
            float* op = (float*)out;
            *reinterpret_cast<float4*>(&op[(size_t)node * 64 + c * 8]) = r0;
            *reinterpret_cast<float4*>(&op[(size_t)node * 64 + c * 8 + 4]) = r1;
        } else {
            u16* op = (u16*)out;
            ushort4 o0 = { f32_to_bf16(r0.x), f32_to_bf16(r0.y), f32_to_bf16(r0.z), f32_to_bf16(r0.w) };
            ushort4 o1 = { f32_to_bf16(r1.x), f32_to_bf16(r1.y), f32_to_bf16(r1.z), f32_to_bf16(r1.w) };
            *reinterpret_cast<ushort4*>(&op[(size_t)node * 64 + c * 8]) = o0;
            *reinterpret_cast<ushort4*>(&op[(size_t)node * 64 + c * 8 + 4]) = o1;
        }
    }
}

extern "C" void kernel_launch(void* const* d_in, const int* in_sizes, int n_in,
                              void* d_out, int out_size, void* d_ws, size_t ws_size,
                              hipStream_t stream) {
    const float* x  = (const float*)d_in[0];
    const float* ea = (const float*)d_in[1];
    const int* eidx = (const int*)d_in[2];
    const float* W1 = (const float*)d_in[3];
    const float* b1 = (const float*)d_in[4];
    const float* W2 = (const float*)d_in[5];
    const float* b2 = (const float*)d_in[6];
    const float* W3 = (const float*)d_in[7];
    const float* b3 = (const float*)d_in[8];

    int N = in_sizes[0] / 64;
    int E = in_sizes[1] / 16;
    const int* src = eidx;
    const int* dst = eidx + E;
    int NB = (N + BKT_NODES - 1) / BKT_NODES;

    char* p = (char*)d_ws;
    auto alloc = [&](size_t bytes) {
        char* r = p;
        p += (bytes + 255) & ~(size_t)255;
        return r;
    };
    int*   row_ptr = (int*)alloc((size_t)(N + 1) * 4);
    int*   bcnt    = (int*)alloc(257 * 4);
    int*   bbase   = (int*)alloc(257 * 4);
    int*   bcur    = (int*)alloc(257 * 4);
    int*   adj_src = (int*)alloc((size_t)E * 4);
    int*   adj_eid = (int*)alloc((size_t)E * 4);
    u16*   eapb    = (u16*)alloc((size_t)N * 16 * 2);
    u16*   wt      = (u16*)alloc((size_t)3 * 128 * PADK * 2);
    u16*   hb      = (u16*)alloc((size_t)N * 64 * 2);
    u16*   Spb     = (u16*)alloc((size_t)N * 64 * 2);
    size_t qsz = (size_t)N * 64 * 2, esz = (size_t)E * 8;
    char*  qe      = alloc(qsz > esz ? qsz : esz);
    u16*   Qb      = (u16*)qe;
    u64*   ebuf    = (u64*)qe;   // alias: consumed by k_csr before Q written

    hipMemsetAsync(bcnt, 0, 257 * 4, stream);

    int gP = (E + PART_EDGES - 1) / PART_EDGES;
    k_hist<<<gP, 256, 0, stream>>>(dst, bcnt, E);
    k_bucket_scan<<<1, 256, 0, stream>>>(bcnt, bbase, bcur, row_ptr, NB, N, E);
    k_part<<<gP, 256, 0, stream>>>(src, dst, bcur, ebuf, E);
    k_csr<<<NB, 512, 0, stream>>>(ebuf, bbase, row_ptr, adj_src, adj_eid, N);

    k_prep_w<<<3, 256, 0, stream>>>(W1, W2, W3, wt);
    k_agg_ea<<<(N + 15) / 16, 256, 0, stream>>>(ea, row_ptr, adj_eid, eapb, N);

    int gT = (N + 31) / 32;
    int gA = (N + 7) / 8;

    k_gemm_mfma<1><<<gT, 256, 0, stream>>>(x,  eapb, wt,              b1, Spb, Qb, N);
    k_aggregate<true,  false><<<gA, 256, 0, stream>>>(Spb, Qb, row_ptr, adj_src, hb, N);
    k_gemm_mfma<0><<<gT, 256, 0, stream>>>(hb, eapb, wt + 128 * PADK, b2, Spb, Qb, N);
    k_aggregate<true,  false><<<gA, 256, 0, stream>>>(Spb, Qb, row_ptr, adj_src, hb, N);
    k_gemm_mfma<0><<<gT, 256, 0, stream>>>(hb, eapb, wt + 256 * PADK, b3, Spb, Qb, N);
    k_aggregate<false, true ><<<gA, 256, 0, stream>>>(Spb, Qb, row_ptr, adj_src, d_out, N);
}